// Round 2
// baseline (6772.522 us; speedup 1.0000x reference)
//
#include <hip/hip_runtime.h>
#include <hip/hip_bf16.h>
#include <math.h>

#define EPS 1e-5f

typedef __hip_bfloat16 bf16;

__device__ __forceinline__ float bf2f(bf16 v) { return __bfloat162float(v); }
// dual-mode input load: isbf=1 -> buffer holds bf16, else f32
__device__ __forceinline__ float ldin(const void* p, size_t i, int isbf) {
    return isbf ? __bfloat162float(((const bf16*)p)[i]) : ((const float*)p)[i];
}

// ---------------------------------------------------------------------------
// Runtime dtype sniffing: true-f32 N(0,1) words have f32 exponent in
// [0x70,0x8E]; bf16-packed pairs read as f32 words have exponent =
// (bf16exp[6:0]<<1)|mantbit -> {0xF6..0xFF,0x00..0x07}. flags[0]=1 => bf16.
// ---------------------------------------------------------------------------
__global__ __launch_bounds__(64) void detect_kernel(const void* __restrict__ x,
                                                    int* __restrict__ flags) {
    const unsigned* w = (const unsigned*)x;
    unsigned word = w[threadIdx.x];
    int e = (word >> 23) & 0xFF;
    bool ok = (word == 0u) || (e >= 0x70 && e <= 0x8E);
    unsigned long long m = __ballot(ok);
    if (threadIdx.x == 0) flags[0] = (__popcll(m) >= 32) ? 0 : 1;
}

// ---------------------------------------------------------------------------
// Ternary-weight distribution prep
// ---------------------------------------------------------------------------
__global__ __launch_bounds__(256) void prep_w_kernel(
    const void* __restrict__ alpha, const void* __restrict__ betta,
    const int* __restrict__ flags,
    float* __restrict__ wm, float* __restrict__ wv, int n)
{
    int i = blockIdx.x * 256 + threadIdx.x;
    if (i >= n) return;
    int fl = flags[0];
    float a = ldin(alpha, i, fl), b = ldin(betta, i, fl);
    float p0 = 1.f / (1.f + expf(-a));
    float p1 = (1.f - p0) / (1.f + expf(-b));
    float m = 2.f * p1 + p0 - 1.f;
    wm[i] = m;
    wv[i] = (1.f - p0) - m * m;
}

// ---------------------------------------------------------------------------
// Direct LR-conv. One thread = one output position (b,oh,ow) x 8 consecutive
// output channels. ACT==0: erf(m/sqrt(2(v+eps))) -> bf16 out.
// ACT==1: m + sqrt(v+eps)*noise -> f32 out.  RAWIN: read x via ldin(flag).
// ---------------------------------------------------------------------------
template<int CI, int STRIDE, int ACT, int RAWIN>
__global__ __launch_bounds__(256) void lr_conv_kernel(
    const void* __restrict__ xraw,       // RAWIN: [B,CI,H,W] f32-or-bf16
    const bf16* __restrict__ xbf,        // !RAWIN: [B,CI,H,W] bf16
    const float* __restrict__ wmv,       // wm [CO,CI,3,3] then wv
    const void* __restrict__ bias,       // [CO] raw
    const void* __restrict__ noise,      // [B,CO,OH,OW] raw (ACT==1)
    const int* __restrict__ flags,
    void* __restrict__ outp,             // bf16 (ACT0) or f32 (ACT1)
    int H, int W, int OH, int OW, int CO)
{
    const int fl = flags[0];
    const float* wm = wmv;
    const float* wv = wmv + (size_t)CO * CI * 9;

    int pos = blockIdx.x * 256 + threadIdx.x;  // B*OH*OW (exact multiple)
    int ow = pos % OW;
    int t = pos / OW;
    int oh = t % OH;
    int b = t / OH;
    int co0 = blockIdx.y * 8;

    float accM[8], accV[8];
#pragma unroll
    for (int j = 0; j < 8; j++) { accM[j] = 0.f; accV[j] = 0.f; }

    int ih0 = oh * STRIDE - 1, iw0 = ow * STRIDE - 1;
    size_t xbase = (size_t)b * CI * H * W;
    const float* wmb = wm + (size_t)co0 * CI * 9;
    const float* wvb = wv + (size_t)co0 * CI * 9;

    for (int ci = 0; ci < CI; ci++) {
        size_t xc = xbase + (size_t)ci * H * W;
        float xr[9];
#pragma unroll
        for (int kh = 0; kh < 3; kh++) {
            int ih = ih0 + kh;
            bool okh = (unsigned)ih < (unsigned)H;
#pragma unroll
            for (int kw = 0; kw < 3; kw++) {
                int iw = iw0 + kw;
                bool ok = okh && ((unsigned)iw < (unsigned)W);
                float v = 0.f;
                if (ok) {
                    size_t idx = xc + (size_t)ih * W + iw;
                    v = RAWIN ? ldin(xraw, idx, fl) : bf2f(xbf[idx]);
                }
                xr[kh * 3 + kw] = v;
            }
        }
        const float* wmc = wmb + ci * 9;
        const float* wvc = wvb + ci * 9;
#pragma unroll
        for (int tap = 0; tap < 9; tap++) {
            float xv = xr[tap];
            float xs = xv * xv;
#pragma unroll
            for (int j = 0; j < 8; j++) {
                accM[j] = fmaf(xv, wmc[(size_t)j * CI * 9 + tap], accM[j]);
                accV[j] = fmaf(xs, wvc[(size_t)j * CI * 9 + tap], accV[j]);
            }
        }
    }

    size_t ohw = (size_t)OH * OW;
    size_t obase = (size_t)b * CO * ohw + (size_t)oh * OW + ow;
#pragma unroll
    for (int j = 0; j < 8; j++) {
        int co = co0 + j;
        float m = accM[j] + ldin(bias, co, fl);
        float v = accV[j];
        size_t oidx = obase + (size_t)co * ohw;
        if (ACT == 0) {
            float o = erff(m / sqrtf(2.f * (v + EPS)));
            ((bf16*)outp)[oidx] = __float2bfloat16(o);
        } else {
            float nz = ldin(noise, oidx, fl);
            ((float*)outp)[oidx] = m + sqrtf(v + EPS) * nz;
        }
    }
}

// ---------------------------------------------------------------------------
// BatchNorm stats: z [256,512,4,4] f32 -> scale/shift per channel
// ---------------------------------------------------------------------------
__global__ __launch_bounds__(256) void bn_stats_kernel(
    const float* __restrict__ z, const void* __restrict__ gamma,
    const void* __restrict__ beta, const int* __restrict__ flags,
    float* __restrict__ sc, float* __restrict__ sh)
{
    int c = blockIdx.x;  // 512
    float s = 0.f, ss = 0.f;
    for (int i = threadIdx.x; i < 4096; i += 256) {
        int b = i >> 4, p = i & 15;
        float zv = z[(((size_t)b * 512 + c) << 4) + p];
        s += zv; ss += zv * zv;
    }
#pragma unroll
    for (int off = 32; off > 0; off >>= 1) {
        s += __shfl_down(s, off);
        ss += __shfl_down(ss, off);
    }
    __shared__ float ls[4], lss[4];
    int wid = threadIdx.x >> 6, lane = threadIdx.x & 63;
    if (lane == 0) { ls[wid] = s; lss[wid] = ss; }
    __syncthreads();
    if (threadIdx.x == 0) {
        int fl = flags[0];
        float S = ls[0] + ls[1] + ls[2] + ls[3];
        float SS = lss[0] + lss[1] + lss[2] + lss[3];
        float mean = S * (1.f / 4096.f);
        float var = SS * (1.f / 4096.f) - mean * mean;
        float scale = ldin(gamma, c, fl) / sqrtf(var + EPS);
        sc[c] = scale;
        sh[c] = ldin(beta, c, fl) - mean * scale;
    }
}

__global__ __launch_bounds__(256) void bn_apply_kernel(
    const float* __restrict__ z, const float* __restrict__ sc,
    const float* __restrict__ sh, bf16* __restrict__ zr)
{
    int i = blockIdx.x * 256 + threadIdx.x;  // 2097152
    int c = (i >> 4) & 511;
    float v = z[i] * sc[c] + sh[c];
    zr[i] = __float2bfloat16(fmaxf(v, 0.f));
}

// ---------------------------------------------------------------------------
// FC1: out[256,1024] = relu(zr[256,8192] @ W[1024,8192]^T + b)
// ---------------------------------------------------------------------------
__global__ __launch_bounds__(256) void fc1_kernel(
    const bf16* __restrict__ A, const void* __restrict__ Wt,
    const void* __restrict__ bias, const int* __restrict__ flags,
    float* __restrict__ out)
{
    const int fl = flags[0];
    __shared__ float As[16][33];
    __shared__ float Bs[16][65];
    int tid = threadIdx.x;
    int mg = tid & 15;
    int og = tid >> 4;
    int m0 = blockIdx.y * 32;
    int o0 = blockIdx.x * 64;

    float acc[2][4];
#pragma unroll
    for (int i = 0; i < 2; i++)
#pragma unroll
        for (int j = 0; j < 4; j++) acc[i][j] = 0.f;

    for (int k0 = 0; k0 < 8192; k0 += 16) {
        {
            int c = tid & 15, r0 = tid >> 4;
#pragma unroll
            for (int i = 0; i < 2; i++) {
                int r = r0 + i * 16;
                As[c][r] = bf2f(A[(size_t)(m0 + r) * 8192 + k0 + c]);
            }
        }
        {
            int c = (tid & 3) * 4, r = tid >> 2;
            size_t sbase = (size_t)(o0 + r) * 8192 + k0 + c;
#pragma unroll
            for (int i = 0; i < 4; i++) Bs[c + i][r] = ldin(Wt, sbase + i, fl);
        }
        __syncthreads();
#pragma unroll
        for (int k = 0; k < 16; k++) {
            float a0 = As[k][mg * 2], a1 = As[k][mg * 2 + 1];
            float b0 = Bs[k][og * 4], b1 = Bs[k][og * 4 + 1];
            float b2 = Bs[k][og * 4 + 2], b3 = Bs[k][og * 4 + 3];
            acc[0][0] = fmaf(a0, b0, acc[0][0]);
            acc[0][1] = fmaf(a0, b1, acc[0][1]);
            acc[0][2] = fmaf(a0, b2, acc[0][2]);
            acc[0][3] = fmaf(a0, b3, acc[0][3]);
            acc[1][0] = fmaf(a1, b0, acc[1][0]);
            acc[1][1] = fmaf(a1, b1, acc[1][1]);
            acc[1][2] = fmaf(a1, b2, acc[1][2]);
            acc[1][3] = fmaf(a1, b3, acc[1][3]);
        }
        __syncthreads();
    }
#pragma unroll
    for (int i = 0; i < 2; i++)
#pragma unroll
        for (int j = 0; j < 4; j++) {
            int m = m0 + mg * 2 + i, o = o0 + og * 4 + j;
            float v = acc[i][j] + ldin(bias, o, fl);
            out[(size_t)m * 1024 + o] = fmaxf(v, 0.f);
        }
}

// ---------------------------------------------------------------------------
// FC2: out[256,10]; dtype of out follows the input flag
// ---------------------------------------------------------------------------
__global__ __launch_bounds__(640) void fc2_kernel(
    const float* __restrict__ A, const void* __restrict__ W,
    const void* __restrict__ bias, const int* __restrict__ flags,
    void* __restrict__ out)
{
    const int fl = flags[0];
    int n = blockIdx.x;
    int o = threadIdx.x >> 6;  // 0..9
    int lane = threadIdx.x & 63;
    const float* a = A + (size_t)n * 1024;
    size_t wbase = (size_t)o * 1024;
    float s = 0.f;
    for (int i = lane; i < 1024; i += 64) s = fmaf(a[i], ldin(W, wbase + i, fl), s);
#pragma unroll
    for (int off = 32; off > 0; off >>= 1) s += __shfl_down(s, off);
    if (lane == 0) {
        float v = s + ldin(bias, o, fl);
        if (fl) ((bf16*)out)[n * 10 + o] = __float2bfloat16(v);
        else    ((float*)out)[n * 10 + o] = v;
    }
}

// ---------------------------------------------------------------------------
extern "C" void kernel_launch(void* const* d_in, const int* in_sizes, int n_in,
                              void* d_out, int out_size, void* d_ws, size_t ws_size,
                              hipStream_t stream)
{
    const void* x = d_in[0];
    const void *al[6], *be[6], *bi[6];
    for (int l = 0; l < 6; l++) {
        al[l] = d_in[1 + 3 * l];
        be[l] = d_in[2 + 3 * l];
        bi[l] = d_in[3 + 3 * l];
    }
    const void* bn_gamma = d_in[19];
    const void* bn_beta  = d_in[20];
    const void* fc1_w = d_in[21];
    const void* fc1_b = d_in[22];
    const void* fc2_w = d_in[23];
    const void* fc2_b = d_in[24];
    const void* noise = d_in[25];

    // ---- workspace layout (byte-based, ~134 MB total) ----
    char* base = (char*)d_ws;
    size_t off = 0;
    auto alloc = [&](size_t bytes) { void* p = base + off; off += (bytes + 255) & ~(size_t)255; return p; };
    int* flags = (int*)alloc(256);
    const size_t Sw[6] = {3456, 147456, 294912, 589824, 1179648, 2359296};
    float* wbuf[6];
    for (int l = 0; l < 6; l++) wbuf[l] = (float*)alloc(2 * Sw[l] * sizeof(float));
    bf16* actA = (bf16*)alloc((size_t)256 * 128 * 32 * 32 * sizeof(bf16));  // 67.1 MB
    bf16* actB = (bf16*)alloc((size_t)256 * 128 * 16 * 16 * sizeof(bf16));  // 16.8 MB
    float* z   = (float*)alloc((size_t)256 * 512 * 16 * sizeof(float));     // 8.4 MB
    bf16* zr   = (bf16*)alloc((size_t)256 * 8192 * sizeof(bf16));           // 4.2 MB
    float* bnsc = (float*)alloc(512 * sizeof(float));
    float* bnsh = (float*)alloc(512 * sizeof(float));
    float* fc1o = (float*)alloc((size_t)256 * 1024 * sizeof(float));

    // dtype sniff (writes flags[0]; all later kernels read it)
    detect_kernel<<<1, 64, 0, stream>>>(x, flags);

    for (int l = 0; l < 6; l++) {
        int n = (int)Sw[l];
        prep_w_kernel<<<(n + 255) / 256, 256, 0, stream>>>(
            al[l], be[l], flags, wbuf[l], wbuf[l] + Sw[l], n);
    }

    // conv stack (NCHW, pad=1)
    lr_conv_kernel<3, 1, 0, 1><<<dim3(1024, 16), 256, 0, stream>>>(
        x, nullptr, wbuf[0], bi[0], nullptr, flags, actA, 32, 32, 32, 32, 128);
    lr_conv_kernel<128, 2, 0, 0><<<dim3(256, 16), 256, 0, stream>>>(
        nullptr, actA, wbuf[1], bi[1], nullptr, flags, actB, 32, 32, 16, 16, 128);
    lr_conv_kernel<128, 1, 0, 0><<<dim3(256, 32), 256, 0, stream>>>(
        nullptr, actB, wbuf[2], bi[2], nullptr, flags, actA, 16, 16, 16, 16, 256);
    lr_conv_kernel<256, 2, 0, 0><<<dim3(64, 32), 256, 0, stream>>>(
        nullptr, actA, wbuf[3], bi[3], nullptr, flags, actB, 16, 16, 8, 8, 256);
    lr_conv_kernel<256, 1, 0, 0><<<dim3(64, 64), 256, 0, stream>>>(
        nullptr, actB, wbuf[4], bi[4], nullptr, flags, actA, 8, 8, 8, 8, 512);
    lr_conv_kernel<512, 2, 1, 0><<<dim3(16, 64), 256, 0, stream>>>(
        nullptr, actA, wbuf[5], bi[5], noise, flags, z, 8, 8, 4, 4, 512);

    // batchnorm + relu
    bn_stats_kernel<<<512, 256, 0, stream>>>(z, bn_gamma, bn_beta, flags, bnsc, bnsh);
    bn_apply_kernel<<<8192, 256, 0, stream>>>(z, bnsc, bnsh, zr);

    // classifier head
    fc1_kernel<<<dim3(16, 8), 256, 0, stream>>>(zr, fc1_w, fc1_b, flags, fc1o);
    fc2_kernel<<<256, 640, 0, stream>>>(fc1o, fc2_w, fc2_b, flags, d_out);
}

// Round 3
// 1696.863 us; speedup vs baseline: 3.9912x; 3.9912x over previous
//
#include <hip/hip_runtime.h>
#include <hip/hip_bf16.h>
#include <math.h>

#define EPS 1e-5f

typedef __hip_bfloat16 bf16;
typedef short s16x8 __attribute__((ext_vector_type(8)));
typedef float f32x4 __attribute__((ext_vector_type(4)));

__device__ __forceinline__ float bf2f(bf16 v) { return __bfloat162float(v); }
__device__ __forceinline__ float ldin(const void* p, size_t i, int isbf) {
    return isbf ? __bfloat162float(((const bf16*)p)[i]) : ((const float*)p)[i];
}
__device__ __forceinline__ float b2f_bits(short s) {
    unsigned u = ((unsigned)(unsigned short)s) << 16;
    return __builtin_bit_cast(float, u);
}
__device__ __forceinline__ short f2b_bits(float f) {
    unsigned u = __builtin_bit_cast(unsigned, f);
    u += 0x7FFFu + ((u >> 16) & 1u);
    return (short)(u >> 16);
}
__device__ __forceinline__ s16x8 sq8(s16x8 a) {
    s16x8 r;
#pragma unroll
    for (int i = 0; i < 8; i++) { float f = b2f_bits(a[i]); r[i] = f2b_bits(f * f); }
    return r;
}

// ---------------------------------------------------------------------------
// dtype sniff (f32 vs bf16-packed inputs); flags[0]=1 => bf16
// ---------------------------------------------------------------------------
__global__ __launch_bounds__(64) void detect_kernel(const void* __restrict__ x,
                                                    int* __restrict__ flags) {
    const unsigned* w = (const unsigned*)x;
    unsigned word = w[threadIdx.x];
    int e = (word >> 23) & 0xFF;
    bool ok = (word == 0u) || (e >= 0x70 && e <= 0x8E);
    unsigned long long m = __ballot(ok);
    if (threadIdx.x == 0) flags[0] = (__popcll(m) >= 32) ? 0 : 1;
}

// ---------------------------------------------------------------------------
// Ternary-weight prep. L1 variant: f32, natural [co][ci][3][3] layout.
// ---------------------------------------------------------------------------
__global__ __launch_bounds__(256) void prep_w_l1(
    const void* __restrict__ alpha, const void* __restrict__ betta,
    const int* __restrict__ flags, float* __restrict__ wmv, int n)
{
    int i = blockIdx.x * 256 + threadIdx.x;
    if (i >= n) return;
    int fl = flags[0];
    float a = ldin(alpha, i, fl), b = ldin(betta, i, fl);
    float p0 = 1.f / (1.f + expf(-a));
    float p1 = (1.f - p0) / (1.f + expf(-b));
    float m = 2.f * p1 + p0 - 1.f;
    wmv[i] = m;
    wmv[n + i] = (1.f - p0) - m * m;
}

// GEMM variant: bf16, reordered to [co][tap][ci] so K=(tap,ci) rows are
// ci-contiguous (matches NHWC activation rows).
__global__ __launch_bounds__(256) void prep_w_r(
    const void* __restrict__ alpha, const void* __restrict__ betta,
    const int* __restrict__ flags, bf16* __restrict__ wmr, bf16* __restrict__ wvr,
    int CI, int n)
{
    int i = blockIdx.x * 256 + threadIdx.x;
    if (i >= n) return;
    int fl = flags[0];
    float a = ldin(alpha, i, fl), b = ldin(betta, i, fl);
    float p0 = 1.f / (1.f + expf(-a));
    float p1 = (1.f - p0) / (1.f + expf(-b));
    float m = 2.f * p1 + p0 - 1.f;
    float v = (1.f - p0) - m * m;
    int cirest = CI * 9;
    int co = i / cirest, rem = i % cirest;
    int ci = rem / 9, tap = rem % 9;
    int o = (co * 9 + tap) * CI + ci;
    wmr[o] = __float2bfloat16(m);
    wvr[o] = __float2bfloat16(v);
}

// fc1 weight permute: W'[o][hw*512+c] = fc1_w[o][c*16+hw]  (bf16 out)
__global__ __launch_bounds__(256) void permute_fc1(
    const void* __restrict__ w, const int* __restrict__ flags, bf16* __restrict__ wp)
{
    int i = blockIdx.x * 256 + threadIdx.x;  // 1024*8192
    int fl = flags[0];
    int o = i >> 13, kp = i & 8191;
    int hw = kp >> 9, c = kp & 511;
    wp[i] = __float2bfloat16(ldin(w, (size_t)o * 8192 + c * 16 + hw, fl));
}

// ---------------------------------------------------------------------------
// Layer 1 direct conv (CI=3), weights broadcast from LDS, NHWC bf16 out.
// ---------------------------------------------------------------------------
__global__ __launch_bounds__(256) void l1_conv(
    const void* __restrict__ x, const float* __restrict__ wmv,
    const void* __restrict__ bias, const int* __restrict__ flags,
    bf16* __restrict__ out)
{
    __shared__ float Wm[216], Wv[216];
    int tid = threadIdx.x;
    int co0 = blockIdx.y * 8;
    if (tid < 216) {
        int j = tid / 27, t = tid % 27;
        Wm[tid] = wmv[(co0 + j) * 27 + t];
        Wv[tid] = wmv[3456 + (co0 + j) * 27 + t];
    }
    __syncthreads();
    const int fl = flags[0];
    int pos = blockIdx.x * 256 + tid;       // B*32*32
    int owp = pos & 31, oh = (pos >> 5) & 31, b = pos >> 10;
    float accM[8], accV[8];
#pragma unroll
    for (int j = 0; j < 8; j++) { accM[j] = 0.f; accV[j] = 0.f; }
    for (int ci = 0; ci < 3; ci++) {
        float xr[9];
#pragma unroll
        for (int kh = 0; kh < 3; kh++) {
            int ih = oh - 1 + kh;
#pragma unroll
            for (int kw = 0; kw < 3; kw++) {
                int iw = owp - 1 + kw;
                bool ok = (unsigned)ih < 32u && (unsigned)iw < 32u;
                xr[kh * 3 + kw] = ok ? ldin(x, ((size_t)(b * 3 + ci) * 32 + ih) * 32 + iw, fl) : 0.f;
            }
        }
#pragma unroll
        for (int tap = 0; tap < 9; tap++) {
            float xv = xr[tap], xs = xv * xv;
#pragma unroll
            for (int j = 0; j < 8; j++) {
                accM[j] = fmaf(xv, Wm[j * 27 + ci * 9 + tap], accM[j]);
                accV[j] = fmaf(xs, Wv[j * 27 + ci * 9 + tap], accV[j]);
            }
        }
    }
#pragma unroll
    for (int j = 0; j < 8; j++) {
        float m = accM[j] + ldin(bias, co0 + j, fl);
        float v = accV[j];
        out[(size_t)pos * 128 + co0 + j] =
            __float2bfloat16(erff(m * rsqrtf(2.f * (v + EPS))));
    }
}

// ---------------------------------------------------------------------------
// Implicit-GEMM LR-conv, bf16 MFMA 16x16x32, NHWC activations.
// Block: 128 positions x 128 co; 4 waves (2x2) of 64x64; dual path (m,v)
// with x^2 fragments squared in-register. K-loop = 9 taps x (CI/32).
// ACT0 -> erf -> bf16 NHWC.  ACT1 -> m + sqrt(v+eps)*noise(NCHW) -> f32 NHWC.
// ---------------------------------------------------------------------------
template<int CI, int CO, int H, int W, int S, int OH, int OW, int ACT>
__global__ __launch_bounds__(256) void conv_gemm(
    const bf16* __restrict__ xin,   // NHWC [B,H,W,CI]
    const bf16* __restrict__ wmr,   // [CO][9][CI]
    const bf16* __restrict__ wvr,
    const void* __restrict__ bias, const void* __restrict__ noise,
    const int* __restrict__ flags, void* __restrict__ outp)
{
    constexpr int OHW = OH * OW;
    __shared__ bf16 Xs[128 * 40];
    __shared__ bf16 Wms[128 * 40];
    __shared__ bf16 Wvs[128 * 40];

    int tid = threadIdx.x;
    int lane = tid & 63, wv_ = tid >> 6;
    int q = lane >> 4, l15 = lane & 15;
    const int pw = (wv_ >> 1) * 64, cw = (wv_ & 1) * 64;
    const int c0 = blockIdx.y * 128;

    // staging roles
    const int xrow_i = tid >> 1, xhalf = tid & 1;   // X: row, 32B half
    const int wrow_i = tid & 127, wpath = tid >> 7; // W: row, path

    int P = blockIdx.x * 128 + xrow_i;
    int b = P / OHW, rr = P % OHW;
    int oh = rr / OW, owp = rr % OW;

    const bf16* wrow_base = (wpath ? wvr : wmr) + (size_t)(c0 + wrow_i) * 9 * CI;
    bf16* wdst = (wpath ? Wvs : Wms) + wrow_i * 40;

    f32x4 accM[4][4], accV[4][4];
#pragma unroll
    for (int i = 0; i < 4; i++)
#pragma unroll
        for (int j = 0; j < 4; j++) {
            accM[i][j] = (f32x4){0.f, 0.f, 0.f, 0.f};
            accV[i][j] = (f32x4){0.f, 0.f, 0.f, 0.f};
        }

    for (int kh = 0; kh < 3; kh++) {
        int ih = oh * S - 1 + kh;
        bool okh = (unsigned)ih < (unsigned)H;
        for (int kw = 0; kw < 3; kw++) {
            int iw = owp * S - 1 + kw;
            bool ok = okh && ((unsigned)iw < (unsigned)W);
            const bf16* xrow = xin + (((size_t)b * H + ih) * W + iw) * CI;
            const bf16* wrow = wrow_base + (kh * 3 + kw) * CI;
            for (int ci0 = 0; ci0 < CI; ci0 += 32) {
                __syncthreads();
                // stage X row half (16 bf16 = 32B)
                {
                    uint4 v0 = {0, 0, 0, 0}, v1 = {0, 0, 0, 0};
                    if (ok) {
                        const uint4* s = (const uint4*)(xrow + ci0 + xhalf * 16);
                        v0 = s[0]; v1 = s[1];
                    }
                    uint4* d = (uint4*)(Xs + xrow_i * 40 + xhalf * 16);
                    d[0] = v0; d[1] = v1;
                }
                // stage W row (32 bf16 = 64B)
                {
                    const uint4* s = (const uint4*)(wrow + ci0);
                    uint4* d = (uint4*)wdst;
                    d[0] = s[0]; d[1] = s[1]; d[2] = s[2]; d[3] = s[3];
                }
                __syncthreads();

                s16x8 a[4], a2[4], bm[4], bv[4];
#pragma unroll
                for (int i = 0; i < 4; i++) {
                    a[i]  = *(const s16x8*)(Xs  + (pw + i * 16 + l15) * 40 + q * 8);
                    a2[i] = sq8(a[i]);
                    bm[i] = *(const s16x8*)(Wms + (cw + i * 16 + l15) * 40 + q * 8);
                    bv[i] = *(const s16x8*)(Wvs + (cw + i * 16 + l15) * 40 + q * 8);
                }
#pragma unroll
                for (int i = 0; i < 4; i++)
#pragma unroll
                    for (int j = 0; j < 4; j++) {
                        accM[i][j] = __builtin_amdgcn_mfma_f32_16x16x32_bf16(a[i],  bm[j], accM[i][j], 0, 0, 0);
                        accV[i][j] = __builtin_amdgcn_mfma_f32_16x16x32_bf16(a2[i], bv[j], accV[i][j], 0, 0, 0);
                    }
            }
        }
    }

    const int fl = flags[0];
#pragma unroll
    for (int j = 0; j < 4; j++) {
        int co = c0 + cw + j * 16 + l15;
        float bs = ldin(bias, co, fl);
#pragma unroll
        for (int i = 0; i < 4; i++) {
            f32x4 m4 = accM[i][j], v4 = accV[i][j];
#pragma unroll
            for (int r = 0; r < 4; r++) {
                int PP = blockIdx.x * 128 + pw + i * 16 + q * 4 + r;
                float mm = m4[r] + bs, vv = v4[r];
                if (ACT == 0) {
                    ((bf16*)outp)[(size_t)PP * CO + co] =
                        __float2bfloat16(erff(mm * rsqrtf(2.f * (vv + EPS))));
                } else {
                    int bb = PP / OHW, hw = PP % OHW;
                    float nz = ldin(noise, ((size_t)bb * CO + co) * OHW + hw, fl);
                    ((float*)outp)[(size_t)PP * CO + co] = mm + sqrtf(vv + EPS) * nz;
                }
            }
        }
    }
}

// ---------------------------------------------------------------------------
// FC1 MFMA GEMM: out[256,1024] = relu(zr[256,8192] @ Wp[1024,8192]^T + b), f32
// Same tile structure, single path.
// ---------------------------------------------------------------------------
__global__ __launch_bounds__(256) void fc1_gemm(
    const bf16* __restrict__ A, const bf16* __restrict__ Wp,
    const void* __restrict__ bias, const int* __restrict__ flags,
    float* __restrict__ out)
{
    __shared__ bf16 Xs[128 * 40];
    __shared__ bf16 Ws[128 * 40];
    int tid = threadIdx.x;
    int lane = tid & 63, wv_ = tid >> 6;
    int q = lane >> 4, l15 = lane & 15;
    const int pw = (wv_ >> 1) * 64, cw = (wv_ & 1) * 64;
    const int p0 = blockIdx.x * 128, c0 = blockIdx.y * 128;
    const int row_i = tid >> 1, half = tid & 1;

    f32x4 acc[4][4];
#pragma unroll
    for (int i = 0; i < 4; i++)
#pragma unroll
        for (int j = 0; j < 4; j++) acc[i][j] = (f32x4){0.f, 0.f, 0.f, 0.f};

    for (int k0 = 0; k0 < 8192; k0 += 32) {
        __syncthreads();
        {
            const uint4* s = (const uint4*)(A + (size_t)(p0 + row_i) * 8192 + k0 + half * 16);
            uint4* d = (uint4*)(Xs + row_i * 40 + half * 16);
            d[0] = s[0]; d[1] = s[1];
        }
        {
            const uint4* s = (const uint4*)(Wp + (size_t)(c0 + row_i) * 8192 + k0 + half * 16);
            uint4* d = (uint4*)(Ws + row_i * 40 + half * 16);
            d[0] = s[0]; d[1] = s[1];
        }
        __syncthreads();
        s16x8 a[4], bb[4];
#pragma unroll
        for (int i = 0; i < 4; i++) {
            a[i]  = *(const s16x8*)(Xs + (pw + i * 16 + l15) * 40 + q * 8);
            bb[i] = *(const s16x8*)(Ws + (cw + i * 16 + l15) * 40 + q * 8);
        }
#pragma unroll
        for (int i = 0; i < 4; i++)
#pragma unroll
            for (int j = 0; j < 4; j++)
                acc[i][j] = __builtin_amdgcn_mfma_f32_16x16x32_bf16(a[i], bb[j], acc[i][j], 0, 0, 0);
    }

    const int fl = flags[0];
#pragma unroll
    for (int j = 0; j < 4; j++) {
        int co = c0 + cw + j * 16 + l15;
        float bs = ldin(bias, co, fl);
#pragma unroll
        for (int i = 0; i < 4; i++) {
            f32x4 m4 = acc[i][j];
#pragma unroll
            for (int r = 0; r < 4; r++) {
                int P = p0 + pw + i * 16 + q * 4 + r;
                out[(size_t)P * 1024 + co] = fmaxf(m4[r] + bs, 0.f);
            }
        }
    }
}

// ---------------------------------------------------------------------------
// BatchNorm over NHWC z [4096 pos][512 c]
// ---------------------------------------------------------------------------
__global__ __launch_bounds__(256) void bn_part(const float* __restrict__ z,
                                               float4* __restrict__ partial)
{
    int blk = blockIdx.x;  // 128
    int t = threadIdx.x;
    float s0 = 0, ss0 = 0, s1 = 0, ss1 = 0;
    for (int p = 0; p < 32; p++) {
        float2 v = ((const float2*)z)[((size_t)(blk * 32 + p)) * 256 + t];
        s0 += v.x; ss0 += v.x * v.x;
        s1 += v.y; ss1 += v.y * v.y;
    }
    partial[blk * 256 + t] = make_float4(s0, ss0, s1, ss1);
}

__global__ __launch_bounds__(512) void bn_fin(
    const float4* __restrict__ partial, const void* __restrict__ gamma,
    const void* __restrict__ beta, const int* __restrict__ flags,
    float* __restrict__ sc, float* __restrict__ sh)
{
    int c = threadIdx.x;  // 512
    float s = 0, ss = 0;
    for (int j = 0; j < 128; j++) {
        float4 pv = partial[j * 256 + (c >> 1)];
        s += (c & 1) ? pv.z : pv.x;
        ss += (c & 1) ? pv.w : pv.y;
    }
    float mean = s * (1.f / 4096.f);
    float var = ss * (1.f / 4096.f) - mean * mean;
    int fl = flags[0];
    float scale = ldin(gamma, c, fl) * rsqrtf(var + EPS);
    sc[c] = scale;
    sh[c] = ldin(beta, c, fl) - mean * scale;
}

__global__ __launch_bounds__(256) void bn_apply(
    const float* __restrict__ z, const float* __restrict__ sc,
    const float* __restrict__ sh, bf16* __restrict__ zr)
{
    int i = blockIdx.x * 256 + threadIdx.x;  // 2097152
    int c = i & 511;
    float v = z[i] * sc[c] + sh[c];
    zr[i] = __float2bfloat16(fmaxf(v, 0.f));
}

// ---------------------------------------------------------------------------
// FC2: out[256,10] = fc1o @ W^T + b
// ---------------------------------------------------------------------------
__global__ __launch_bounds__(640) void fc2_kernel(
    const float* __restrict__ A, const void* __restrict__ W,
    const void* __restrict__ bias, const int* __restrict__ flags,
    void* __restrict__ out)
{
    const int fl = flags[0];
    int n = blockIdx.x;
    int o = threadIdx.x >> 6;  // 0..9
    int lane = threadIdx.x & 63;
    const float* a = A + (size_t)n * 1024;
    size_t wbase = (size_t)o * 1024;
    float s = 0.f;
    for (int i = lane; i < 1024; i += 64) s = fmaf(a[i], ldin(W, wbase + i, fl), s);
#pragma unroll
    for (int off = 32; off > 0; off >>= 1) s += __shfl_down(s, off);
    if (lane == 0) {
        float v = s + ldin(bias, o, fl);
        if (fl) ((bf16*)out)[n * 10 + o] = __float2bfloat16(v);
        else    ((float*)out)[n * 10 + o] = v;
    }
}

// ---------------------------------------------------------------------------
extern "C" void kernel_launch(void* const* d_in, const int* in_sizes, int n_in,
                              void* d_out, int out_size, void* d_ws, size_t ws_size,
                              hipStream_t stream)
{
    const void* x = d_in[0];
    const void *al[6], *be[6], *bi[6];
    for (int l = 0; l < 6; l++) {
        al[l] = d_in[1 + 3 * l];
        be[l] = d_in[2 + 3 * l];
        bi[l] = d_in[3 + 3 * l];
    }
    const void* bn_gamma = d_in[19];
    const void* bn_beta  = d_in[20];
    const void* fc1_w = d_in[21];
    const void* fc1_b = d_in[22];
    const void* fc2_w = d_in[23];
    const void* fc2_b = d_in[24];
    const void* noise = d_in[25];

    // ---- workspace (~134 MB) ----
    char* base = (char*)d_ws;
    size_t off = 0;
    auto alloc = [&](size_t bytes) { void* p = base + off; off += (bytes + 255) & ~(size_t)255; return p; };
    int* flags = (int*)alloc(256);
    float* w1 = (float*)alloc(2 * 3456 * sizeof(float));
    const int SwCI[5] = {128, 128, 256, 256, 512};
    const size_t Sw[5] = {147456, 294912, 589824, 1179648, 2359296};
    bf16 *wmr[5], *wvr[5];
    for (int l = 0; l < 5; l++) {
        wmr[l] = (bf16*)alloc(Sw[l] * sizeof(bf16));
        wvr[l] = (bf16*)alloc(Sw[l] * sizeof(bf16));
    }
    bf16* actA = (bf16*)alloc((size_t)256 * 1024 * 128 * sizeof(bf16));  // 67 MB
    bf16* actB = (bf16*)alloc((size_t)256 * 256 * 128 * sizeof(bf16));   // 16.8 MB
    float* z   = (float*)alloc((size_t)4096 * 512 * sizeof(float));      // 8.4 MB
    bf16* zr   = (bf16*)alloc((size_t)256 * 8192 * sizeof(bf16));        // 4.2 MB
    bf16* Wp   = (bf16*)alloc((size_t)1024 * 8192 * sizeof(bf16));       // 16.8 MB
    float4* part = (float4*)alloc((size_t)128 * 256 * sizeof(float4));   // 0.5 MB
    float* bnsc = (float*)alloc(512 * sizeof(float));
    float* bnsh = (float*)alloc(512 * sizeof(float));
    float* fc1o = (float*)alloc((size_t)256 * 1024 * sizeof(float));     // 1 MB

    detect_kernel<<<1, 64, 0, stream>>>(x, flags);

    prep_w_l1<<<14, 256, 0, stream>>>(al[0], be[0], flags, w1, 3456);
    for (int l = 0; l < 5; l++) {
        int n = (int)Sw[l];
        prep_w_r<<<(n + 255) / 256, 256, 0, stream>>>(
            al[l + 1], be[l + 1], flags, wmr[l], wvr[l], SwCI[l], n);
    }
    permute_fc1<<<32768, 256, 0, stream>>>(fc1_w, flags, Wp);

    // layer 1: direct, NHWC bf16 out
    l1_conv<<<dim3(1024, 16), 256, 0, stream>>>(x, w1, bi[0], flags, actA);

    // layers 2..6: implicit-GEMM MFMA
    conv_gemm<128, 128, 32, 32, 2, 16, 16, 0><<<dim3(512, 1), 256, 0, stream>>>(
        actA, wmr[0], wvr[0], bi[1], nullptr, flags, actB);
    conv_gemm<128, 256, 16, 16, 1, 16, 16, 0><<<dim3(512, 2), 256, 0, stream>>>(
        actB, wmr[1], wvr[1], bi[2], nullptr, flags, actA);
    conv_gemm<256, 256, 16, 16, 2, 8, 8, 0><<<dim3(128, 2), 256, 0, stream>>>(
        actA, wmr[2], wvr[2], bi[3], nullptr, flags, actB);
    conv_gemm<256, 512, 8, 8, 1, 8, 8, 0><<<dim3(128, 4), 256, 0, stream>>>(
        actB, wmr[3], wvr[3], bi[4], nullptr, flags, actA);
    conv_gemm<512, 512, 8, 8, 2, 4, 4, 1><<<dim3(32, 4), 256, 0, stream>>>(
        actA, wmr[4], wvr[4], bi[5], noise, flags, z);

    // batchnorm + relu (NHWC == fc1 k' order)
    bn_part<<<128, 256, 0, stream>>>(z, part);
    bn_fin<<<1, 512, 0, stream>>>(part, bn_gamma, bn_beta, flags, bnsc, bnsh);
    bn_apply<<<8192, 256, 0, stream>>>(z, bnsc, bnsh, zr);

    // classifier head
    fc1_gemm<<<dim3(2, 8), 256, 0, stream>>>(zr, Wp, fc1_b, flags, fc1o);
    fc2_kernel<<<256, 640, 0, stream>>>(fc1o, fc2_w, fc2_b, flags, d_out);
}

// Round 5
// 1218.570 us; speedup vs baseline: 5.5578x; 1.3925x over previous
//
#include <hip/hip_runtime.h>
#include <hip/hip_bf16.h>
#include <math.h>

#define EPS 1e-5f

typedef __hip_bfloat16 bf16;
typedef short s16x8 __attribute__((ext_vector_type(8)));
typedef float f32x4 __attribute__((ext_vector_type(4)));

__device__ __forceinline__ float bf2f(bf16 v) { return __bfloat162float(v); }
__device__ __forceinline__ float ldin(const void* p, size_t i, int isbf) {
    return isbf ? __bfloat162float(((const bf16*)p)[i]) : ((const float*)p)[i];
}
__device__ __forceinline__ float b2f_bits(short s) {
    unsigned u = ((unsigned)(unsigned short)s) << 16;
    return __builtin_bit_cast(float, u);
}
__device__ __forceinline__ short f2b_bits(float f) {
    unsigned u = __builtin_bit_cast(unsigned, f);
    u += 0x7FFFu + ((u >> 16) & 1u);
    return (short)(u >> 16);
}
__device__ __forceinline__ s16x8 sq8(s16x8 a) {
    s16x8 r;
#pragma unroll
    for (int i = 0; i < 8; i++) { float f = b2f_bits(a[i]); r[i] = f2b_bits(f * f); }
    return r;
}

// ---------------------------------------------------------------------------
// dtype sniff (f32 vs bf16-packed inputs); flags[0]=1 => bf16
// ---------------------------------------------------------------------------
__global__ __launch_bounds__(64) void detect_kernel(const void* __restrict__ x,
                                                    int* __restrict__ flags) {
    const unsigned* w = (const unsigned*)x;
    unsigned word = w[threadIdx.x];
    int e = (word >> 23) & 0xFF;
    bool ok = (word == 0u) || (e >= 0x70 && e <= 0x8E);
    unsigned long long m = __ballot(ok);
    if (threadIdx.x == 0) flags[0] = (__popcll(m) >= 32) ? 0 : 1;
}

// ---------------------------------------------------------------------------
// Ternary-weight prep. L1: f32 natural [co][ci][3][3]; GEMM: bf16 [co][tap][ci]
// ---------------------------------------------------------------------------
__global__ __launch_bounds__(256) void prep_w_l1(
    const void* __restrict__ alpha, const void* __restrict__ betta,
    const int* __restrict__ flags, float* __restrict__ wmv, int n)
{
    int i = blockIdx.x * 256 + threadIdx.x;
    if (i >= n) return;
    int fl = flags[0];
    float a = ldin(alpha, i, fl), b = ldin(betta, i, fl);
    float p0 = 1.f / (1.f + expf(-a));
    float p1 = (1.f - p0) / (1.f + expf(-b));
    float m = 2.f * p1 + p0 - 1.f;
    wmv[i] = m;
    wmv[n + i] = (1.f - p0) - m * m;
}

__global__ __launch_bounds__(256) void prep_w_r(
    const void* __restrict__ alpha, const void* __restrict__ betta,
    const int* __restrict__ flags, bf16* __restrict__ wmr, bf16* __restrict__ wvr,
    int CI, int n)
{
    int i = blockIdx.x * 256 + threadIdx.x;
    if (i >= n) return;
    int fl = flags[0];
    float a = ldin(alpha, i, fl), b = ldin(betta, i, fl);
    float p0 = 1.f / (1.f + expf(-a));
    float p1 = (1.f - p0) / (1.f + expf(-b));
    float m = 2.f * p1 + p0 - 1.f;
    float v = (1.f - p0) - m * m;
    int cirest = CI * 9;
    int co = i / cirest, rem = i % cirest;
    int ci = rem / 9, tap = rem % 9;
    int o = (co * 9 + tap) * CI + ci;
    wmr[o] = __float2bfloat16(m);
    wvr[o] = __float2bfloat16(v);
}

// ---------------------------------------------------------------------------
// fc1 weight permute via LDS tile transpose:
// W'[o][hw*512+c] = fc1_w[o][c*16+hw]. Coalesced reads (64B/thread runs),
// conflict-free LDS (write bank = c%32, lane-distinct), coalesced bf16 writes.
// ---------------------------------------------------------------------------
__global__ __launch_bounds__(256) void permute_fc1(
    const void* __restrict__ w, const int* __restrict__ flags, bf16* __restrict__ wp)
{
    __shared__ float L[8192];
    const int fl = flags[0];
    int tid = threadIdx.x;
    int o = blockIdx.x;
    size_t srow = (size_t)o * 8192;
    for (int c = tid; c < 512; c += 256) {
        float v[16];
        if (fl) {
            const uint4* s = (const uint4*)((const bf16*)w + srow + c * 16);
            uint4 u0 = s[0], u1 = s[1];
            const unsigned short* h0 = (const unsigned short*)&u0;
            const unsigned short* h1 = (const unsigned short*)&u1;
#pragma unroll
            for (int j = 0; j < 8; j++) { v[j] = b2f_bits((short)h0[j]); v[8 + j] = b2f_bits((short)h1[j]); }
        } else {
            const float4* s = (const float4*)((const float*)w + srow + c * 16);
#pragma unroll
            for (int j = 0; j < 4; j++) {
                float4 t4 = s[j];
                v[j * 4 + 0] = t4.x; v[j * 4 + 1] = t4.y; v[j * 4 + 2] = t4.z; v[j * 4 + 3] = t4.w;
            }
        }
#pragma unroll
        for (int hw = 0; hw < 16; hw++) L[hw * 512 + c] = v[hw];
    }
    __syncthreads();
    for (int j = 0; j < 32; j++) {
        int idx = j * 256 + tid;
        wp[srow + idx] = __float2bfloat16(L[idx]);
    }
}

// ---------------------------------------------------------------------------
// Layer 1 direct conv (CI=3). Block = 64 positions x 128 channels.
// x taps staged once in LDS (broadcast reads); per-channel weights in regs;
// coalesced NHWC bf16 writes (wave = 128B contiguous).
// ---------------------------------------------------------------------------
__global__ __launch_bounds__(256) void l1_conv(
    const void* __restrict__ x, const float* __restrict__ wmv,
    const void* __restrict__ bias, const int* __restrict__ flags,
    bf16* __restrict__ out)
{
    __shared__ float Xs[64][28];
    const int fl = flags[0];
    int tid = threadIdx.x;
    int pos0 = blockIdx.x * 64;           // 64 | 1024 -> same batch b
    int b = pos0 >> 10;
    for (int u = tid; u < 576; u += 256) {
        int p = u / 9, r = u - p * 9;
        int ci = r / 3, kh = r - ci * 3;
        int pos = pos0 + p;
        int oh = (pos >> 5) & 31, ow = pos & 31;
        int ih = oh - 1 + kh;
        bool okh = (unsigned)ih < 32u;
        size_t base = ((size_t)(b * 3 + ci) * 32 + ih) * 32;
#pragma unroll
        for (int kw = 0; kw < 3; kw++) {
            int iw = ow - 1 + kw;
            float v = (okh && (unsigned)iw < 32u) ? ldin(x, base + iw, fl) : 0.f;
            Xs[p][ci * 9 + kh * 3 + kw] = v;
        }
    }
    int c = tid & 127, pg = tid >> 7;
    float wm[27], wv[27];
#pragma unroll
    for (int k = 0; k < 27; k++) {
        wm[k] = wmv[c * 27 + k];
        wv[k] = wmv[3456 + c * 27 + k];
    }
    float bs = ldin(bias, c, fl);
    __syncthreads();
    for (int it = 0; it < 32; it++) {
        int p = it * 2 + pg;
        float aM = 0.f, aV = 0.f;
#pragma unroll
        for (int k = 0; k < 27; k++) {
            float xv = Xs[p][k];
            aM = fmaf(xv, wm[k], aM);
            aV = fmaf(xv * xv, wv[k], aV);
        }
        out[(size_t)(pos0 + p) * 128 + c] =
            __float2bfloat16(erff((aM + bs) * rsqrtf(2.f * (aV + EPS))));
    }
}

// ---------------------------------------------------------------------------
// Implicit-GEMM LR-conv, bf16 MFMA 16x16x32, NHWC activations.
// ---------------------------------------------------------------------------
template<int CI, int CO, int H, int W, int S, int OH, int OW, int ACT>
__global__ __launch_bounds__(256) void conv_gemm(
    const bf16* __restrict__ xin,   // NHWC [B,H,W,CI]
    const bf16* __restrict__ wmr,   // [CO][9][CI]
    const bf16* __restrict__ wvr,
    const void* __restrict__ bias, const void* __restrict__ noise,
    const int* __restrict__ flags, void* __restrict__ outp)
{
    constexpr int OHW = OH * OW;
    __shared__ bf16 Xs[128 * 40];
    __shared__ bf16 Wms[128 * 40];
    __shared__ bf16 Wvs[128 * 40];

    int tid = threadIdx.x;
    int lane = tid & 63, wv_ = tid >> 6;
    int q = lane >> 4, l15 = lane & 15;
    const int pw = (wv_ >> 1) * 64, cw = (wv_ & 1) * 64;
    const int c0 = blockIdx.y * 128;

    const int xrow_i = tid >> 1, xhalf = tid & 1;
    const int wrow_i = tid & 127, wpath = tid >> 7;

    int P = blockIdx.x * 128 + xrow_i;
    int b = P / OHW, rr = P % OHW;
    int oh = rr / OW, owp = rr % OW;

    const bf16* wrow_base = (wpath ? wvr : wmr) + (size_t)(c0 + wrow_i) * 9 * CI;
    bf16* wdst = (wpath ? Wvs : Wms) + wrow_i * 40;

    f32x4 accM[4][4], accV[4][4];
#pragma unroll
    for (int i = 0; i < 4; i++)
#pragma unroll
        for (int j = 0; j < 4; j++) {
            accM[i][j] = (f32x4){0.f, 0.f, 0.f, 0.f};
            accV[i][j] = (f32x4){0.f, 0.f, 0.f, 0.f};
        }

    for (int kh = 0; kh < 3; kh++) {
        int ih = oh * S - 1 + kh;
        bool okh = (unsigned)ih < (unsigned)H;
        for (int kw = 0; kw < 3; kw++) {
            int iw = owp * S - 1 + kw;
            bool ok = okh && ((unsigned)iw < (unsigned)W);
            const bf16* xrow = xin + (((size_t)b * H + ih) * W + iw) * CI;
            const bf16* wrow = wrow_base + (kh * 3 + kw) * CI;
            for (int ci0 = 0; ci0 < CI; ci0 += 32) {
                __syncthreads();
                {
                    uint4 v0 = {0, 0, 0, 0}, v1 = {0, 0, 0, 0};
                    if (ok) {
                        const uint4* s = (const uint4*)(xrow + ci0 + xhalf * 16);
                        v0 = s[0]; v1 = s[1];
                    }
                    uint4* d = (uint4*)(Xs + xrow_i * 40 + xhalf * 16);
                    d[0] = v0; d[1] = v1;
                }
                {
                    const uint4* s = (const uint4*)(wrow + ci0);
                    uint4* d = (uint4*)wdst;
                    d[0] = s[0]; d[1] = s[1]; d[2] = s[2]; d[3] = s[3];
                }
                __syncthreads();

                s16x8 a[4], a2[4], bm[4], bv[4];
#pragma unroll
                for (int i = 0; i < 4; i++) {
                    a[i]  = *(const s16x8*)(Xs  + (pw + i * 16 + l15) * 40 + q * 8);
                    a2[i] = sq8(a[i]);
                    bm[i] = *(const s16x8*)(Wms + (cw + i * 16 + l15) * 40 + q * 8);
                    bv[i] = *(const s16x8*)(Wvs + (cw + i * 16 + l15) * 40 + q * 8);
                }
#pragma unroll
                for (int i = 0; i < 4; i++)
#pragma unroll
                    for (int j = 0; j < 4; j++) {
                        accM[i][j] = __builtin_amdgcn_mfma_f32_16x16x32_bf16(a[i],  bm[j], accM[i][j], 0, 0, 0);
                        accV[i][j] = __builtin_amdgcn_mfma_f32_16x16x32_bf16(a2[i], bv[j], accV[i][j], 0, 0, 0);
                    }
            }
        }
    }

    const int fl = flags[0];
#pragma unroll
    for (int j = 0; j < 4; j++) {
        int co = c0 + cw + j * 16 + l15;
        float bs = ldin(bias, co, fl);
#pragma unroll
        for (int i = 0; i < 4; i++) {
            f32x4 m4 = accM[i][j], v4 = accV[i][j];
#pragma unroll
            for (int r = 0; r < 4; r++) {
                int PP = blockIdx.x * 128 + pw + i * 16 + q * 4 + r;
                float mm = m4[r] + bs, vv = v4[r];
                if (ACT == 0) {
                    ((bf16*)outp)[(size_t)PP * CO + co] =
                        __float2bfloat16(erff(mm * rsqrtf(2.f * (vv + EPS))));
                } else {
                    int bb = PP / OHW, hw = PP % OHW;
                    float nz = ldin(noise, ((size_t)bb * CO + co) * OHW + hw, fl);
                    ((float*)outp)[(size_t)PP * CO + co] = mm + sqrtf(vv + EPS) * nz;
                }
            }
        }
    }
}

// ---------------------------------------------------------------------------
// FC1 split-K MFMA GEMM: partial[ks][256][1024] over K-slice of 1024
// ---------------------------------------------------------------------------
__global__ __launch_bounds__(256) void fc1_gemm_sk(
    const bf16* __restrict__ A, const bf16* __restrict__ Wp,
    float* __restrict__ part)
{
    __shared__ bf16 Xs[128 * 40];
    __shared__ bf16 Ws[128 * 40];
    int tid = threadIdx.x;
    int lane = tid & 63, wv_ = tid >> 6;
    int q = lane >> 4, l15 = lane & 15;
    const int pw = (wv_ >> 1) * 64, cw = (wv_ & 1) * 64;
    const int p0 = blockIdx.x * 128, c0 = blockIdx.y * 128;
    const int kb = blockIdx.z * 1024;
    const int row_i = tid >> 1, half = tid & 1;

    f32x4 acc[4][4];
#pragma unroll
    for (int i = 0; i < 4; i++)
#pragma unroll
        for (int j = 0; j < 4; j++) acc[i][j] = (f32x4){0.f, 0.f, 0.f, 0.f};

    for (int k0 = kb; k0 < kb + 1024; k0 += 32) {
        __syncthreads();
        {
            const uint4* s = (const uint4*)(A + (size_t)(p0 + row_i) * 8192 + k0 + half * 16);
            uint4* d = (uint4*)(Xs + row_i * 40 + half * 16);
            d[0] = s[0]; d[1] = s[1];
        }
        {
            const uint4* s = (const uint4*)(Wp + (size_t)(c0 + row_i) * 8192 + k0 + half * 16);
            uint4* d = (uint4*)(Ws + row_i * 40 + half * 16);
            d[0] = s[0]; d[1] = s[1];
        }
        __syncthreads();
        s16x8 a[4], bb[4];
#pragma unroll
        for (int i = 0; i < 4; i++) {
            a[i]  = *(const s16x8*)(Xs + (pw + i * 16 + l15) * 40 + q * 8);
            bb[i] = *(const s16x8*)(Ws + (cw + i * 16 + l15) * 40 + q * 8);
        }
#pragma unroll
        for (int i = 0; i < 4; i++)
#pragma unroll
            for (int j = 0; j < 4; j++)
                acc[i][j] = __builtin_amdgcn_mfma_f32_16x16x32_bf16(a[i], bb[j], acc[i][j], 0, 0, 0);
    }

    float* pbase = part + (size_t)blockIdx.z * 256 * 1024;
#pragma unroll
    for (int j = 0; j < 4; j++) {
        int co = c0 + cw + j * 16 + l15;
#pragma unroll
        for (int i = 0; i < 4; i++) {
            f32x4 m4 = acc[i][j];
#pragma unroll
            for (int r = 0; r < 4; r++) {
                int P = p0 + pw + i * 16 + q * 4 + r;
                pbase[(size_t)P * 1024 + co] = m4[r];
            }
        }
    }
}

__global__ __launch_bounds__(256) void fc1_reduce(
    const float* __restrict__ part, const void* __restrict__ bias,
    const int* __restrict__ flags, float* __restrict__ out)
{
    int i = blockIdx.x * 256 + threadIdx.x;  // 262144
    float s = 0.f;
#pragma unroll
    for (int k = 0; k < 8; k++) s += part[(size_t)k * 262144 + i];
    out[i] = fmaxf(s + ldin(bias, i & 1023, flags[0]), 0.f);
}

// ---------------------------------------------------------------------------
// BatchNorm over NHWC z [4096 pos][512 c]
// ---------------------------------------------------------------------------
__global__ __launch_bounds__(256) void bn_part(const float* __restrict__ z,
                                               float4* __restrict__ partial)
{
    int blk = blockIdx.x;  // 128
    int t = threadIdx.x;
    float s0 = 0, ss0 = 0, s1 = 0, ss1 = 0;
    for (int p = 0; p < 32; p++) {
        float2 v = ((const float2*)z)[((size_t)(blk * 32 + p)) * 256 + t];
        s0 += v.x; ss0 += v.x * v.x;
        s1 += v.y; ss1 += v.y * v.y;
    }
    partial[blk * 256 + t] = make_float4(s0, ss0, s1, ss1);
}

__global__ __launch_bounds__(512) void bn_fin(
    const float4* __restrict__ partial, const void* __restrict__ gamma,
    const void* __restrict__ beta, const int* __restrict__ flags,
    float* __restrict__ sc, float* __restrict__ sh)
{
    int c = threadIdx.x;  // 512
    float s = 0, ss = 0;
    for (int j = 0; j < 128; j++) {
        float4 pv = partial[j * 256 + (c >> 1)];
        s += (c & 1) ? pv.z : pv.x;
        ss += (c & 1) ? pv.w : pv.y;
    }
    float mean = s * (1.f / 4096.f);
    float var = ss * (1.f / 4096.f) - mean * mean;
    int fl = flags[0];
    float scale = ldin(gamma, c, fl) * rsqrtf(var + EPS);
    sc[c] = scale;
    sh[c] = ldin(beta, c, fl) - mean * scale;
}

__global__ __launch_bounds__(256) void bn_apply(
    const float* __restrict__ z, const float* __restrict__ sc,
    const float* __restrict__ sh, bf16* __restrict__ zr)
{
    int i = blockIdx.x * 256 + threadIdx.x;  // 2097152
    int c = i & 511;
    float v = z[i] * sc[c] + sh[c];
    zr[i] = __float2bfloat16(fmaxf(v, 0.f));
}

// ---------------------------------------------------------------------------
// FC2: out[256,10] = fc1o @ W^T + b
// ---------------------------------------------------------------------------
__global__ __launch_bounds__(640) void fc2_kernel(
    const float* __restrict__ A, const void* __restrict__ W,
    const void* __restrict__ bias, const int* __restrict__ flags,
    void* __restrict__ out)
{
    const int fl = flags[0];
    int n = blockIdx.x;
    int o = threadIdx.x >> 6;  // 0..9
    int lane = threadIdx.x & 63;
    const float* a = A + (size_t)n * 1024;
    size_t wbase = (size_t)o * 1024;
    float s = 0.f;
    for (int i = lane; i < 1024; i += 64) s = fmaf(a[i], ldin(W, wbase + i, fl), s);
#pragma unroll
    for (int off = 32; off > 0; off >>= 1) s += __shfl_down(s, off);
    if (lane == 0) {
        float v = s + ldin(bias, o, fl);
        if (fl) ((bf16*)out)[n * 10 + o] = __float2bfloat16(v);
        else    ((float*)out)[n * 10 + o] = v;
    }
}

// ---------------------------------------------------------------------------
extern "C" void kernel_launch(void* const* d_in, const int* in_sizes, int n_in,
                              void* d_out, int out_size, void* d_ws, size_t ws_size,
                              hipStream_t stream)
{
    const void* x = d_in[0];
    const void *al[6], *be[6], *bi[6];
    for (int l = 0; l < 6; l++) {
        al[l] = d_in[1 + 3 * l];
        be[l] = d_in[2 + 3 * l];
        bi[l] = d_in[3 + 3 * l];
    }
    const void* bn_gamma = d_in[19];
    const void* bn_beta  = d_in[20];
    const void* fc1_w = d_in[21];
    const void* fc1_b = d_in[22];
    const void* fc2_w = d_in[23];
    const void* fc2_b = d_in[24];
    const void* noise = d_in[25];

    // ---- workspace (~134 MB) ----
    char* base = (char*)d_ws;
    size_t off = 0;
    auto alloc = [&](size_t bytes) { void* p = base + off; off += (bytes + 255) & ~(size_t)255; return p; };
    int* flags = (int*)alloc(256);
    float* w1 = (float*)alloc(2 * 3456 * sizeof(float));
    const int SwCI[5] = {128, 128, 256, 256, 512};
    const size_t Sw[5] = {147456, 294912, 589824, 1179648, 2359296};
    bf16 *wmr[5], *wvr[5];
    for (int l = 0; l < 5; l++) {
        wmr[l] = (bf16*)alloc(Sw[l] * sizeof(bf16));
        wvr[l] = (bf16*)alloc(Sw[l] * sizeof(bf16));
    }
    bf16* actA = (bf16*)alloc((size_t)256 * 1024 * 128 * sizeof(bf16));  // 67 MB
    bf16* actB = (bf16*)alloc((size_t)256 * 256 * 128 * sizeof(bf16));   // 16.8 MB
    float* z   = (float*)alloc((size_t)4096 * 512 * sizeof(float));      // 8.4 MB
    bf16* zr   = (bf16*)alloc((size_t)256 * 8192 * sizeof(bf16));        // 4.2 MB
    bf16* Wp   = (bf16*)alloc((size_t)1024 * 8192 * sizeof(bf16));       // 16.8 MB
    float4* part = (float4*)alloc((size_t)128 * 256 * sizeof(float4));   // 0.5 MB
    float* bnsc = (float*)alloc(512 * sizeof(float));
    float* bnsh = (float*)alloc(512 * sizeof(float));
    float* fc1o = (float*)alloc((size_t)256 * 1024 * sizeof(float));     // 1 MB
    // fc1 split-K partials reuse actB (free after conv layer 6): 8.4 MB f32
    float* fc1part = (float*)actB;

    detect_kernel<<<1, 64, 0, stream>>>(x, flags);

    prep_w_l1<<<14, 256, 0, stream>>>(al[0], be[0], flags, w1, 3456);
    for (int l = 0; l < 5; l++) {
        int n = (int)Sw[l];
        prep_w_r<<<(n + 255) / 256, 256, 0, stream>>>(
            al[l + 1], be[l + 1], flags, wmr[l], wvr[l], SwCI[l], n);
    }
    permute_fc1<<<1024, 256, 0, stream>>>(fc1_w, flags, Wp);

    // layer 1: direct, NHWC bf16 out, coalesced
    l1_conv<<<4096, 256, 0, stream>>>(x, w1, bi[0], flags, actA);

    // layers 2..6: implicit-GEMM MFMA
    conv_gemm<128, 128, 32, 32, 2, 16, 16, 0><<<dim3(512, 1), 256, 0, stream>>>(
        actA, wmr[0], wvr[0], bi[1], nullptr, flags, actB);
    conv_gemm<128, 256, 16, 16, 1, 16, 16, 0><<<dim3(512, 2), 256, 0, stream>>>(
        actB, wmr[1], wvr[1], bi[2], nullptr, flags, actA);
    conv_gemm<256, 256, 16, 16, 2, 8, 8, 0><<<dim3(128, 2), 256, 0, stream>>>(
        actA, wmr[2], wvr[2], bi[3], nullptr, flags, actB);
    conv_gemm<256, 512, 8, 8, 1, 8, 8, 0><<<dim3(128, 4), 256, 0, stream>>>(
        actB, wmr[3], wvr[3], bi[4], nullptr, flags, actA);
    conv_gemm<512, 512, 8, 8, 2, 4, 4, 1><<<dim3(32, 4), 256, 0, stream>>>(
        actA, wmr[4], wvr[4], bi[5], noise, flags, z);

    // batchnorm + relu (NHWC == fc1 k' order)
    bn_part<<<128, 256, 0, stream>>>(z, part);
    bn_fin<<<1, 512, 0, stream>>>(part, bn_gamma, bn_beta, flags, bnsc, bnsh);
    bn_apply<<<8192, 256, 0, stream>>>(z, bnsc, bnsh, zr);

    // classifier head (split-K x8 into fc1part, then reduce+bias+relu)
    fc1_gemm_sk<<<dim3(2, 8, 8), 256, 0, stream>>>(zr, Wp, fc1part);
    fc1_reduce<<<1024, 256, 0, stream>>>(fc1part, fc1_b, flags, fc1o);
    fc2_kernel<<<256, 640, 0, stream>>>(fc1o, fc2_w, fc2_b, flags, d_out);
}

// Round 9
// 921.964 us; speedup vs baseline: 7.3458x; 1.3217x over previous
//
#include <hip/hip_runtime.h>
#include <hip/hip_bf16.h>
#include <math.h>

#define EPS 1e-5f

typedef __hip_bfloat16 bf16;
typedef short s16x8 __attribute__((ext_vector_type(8)));
typedef float f32x4 __attribute__((ext_vector_type(4)));

__device__ __forceinline__ float bf2f(bf16 v) { return __bfloat162float(v); }
__device__ __forceinline__ float ldin(const void* p, size_t i, int isbf) {
    return isbf ? __bfloat162float(((const bf16*)p)[i]) : ((const float*)p)[i];
}
__device__ __forceinline__ float b2f_bits(short s) {
    unsigned u = ((unsigned)(unsigned short)s) << 16;
    return __builtin_bit_cast(float, u);
}
__device__ __forceinline__ short f2b_bits(float f) {
    unsigned u = __builtin_bit_cast(unsigned, f);
    u += 0x7FFFu + ((u >> 16) & 1u);
    return (short)(u >> 16);
}
__device__ __forceinline__ s16x8 sq8(s16x8 a) {
    s16x8 r;
#pragma unroll
    for (int i = 0; i < 8; i++) { float f = b2f_bits(a[i]); r[i] = f2b_bits(f * f); }
    return r;
}

// ---------------------------------------------------------------------------
// dtype sniff (f32 vs bf16-packed inputs); flags[0]=1 => bf16
// ---------------------------------------------------------------------------
__global__ __launch_bounds__(64) void detect_kernel(const void* __restrict__ x,
                                                    int* __restrict__ flags) {
    const unsigned* w = (const unsigned*)x;
    unsigned word = w[threadIdx.x];
    int e = (word >> 23) & 0xFF;
    bool ok = (word == 0u) || (e >= 0x70 && e <= 0x8E);
    unsigned long long m = __ballot(ok);
    if (threadIdx.x == 0) flags[0] = (__popcll(m) >= 32) ? 0 : 1;
}

// ---------------------------------------------------------------------------
// Ternary-weight prep. L1: f32 natural [co][ci][3][3]; GEMM: bf16 [co][tap][ci]
// ---------------------------------------------------------------------------
__global__ __launch_bounds__(256) void prep_w_l1(
    const void* __restrict__ alpha, const void* __restrict__ betta,
    const int* __restrict__ flags, float* __restrict__ wmv, int n)
{
    int i = blockIdx.x * 256 + threadIdx.x;
    if (i >= n) return;
    int fl = flags[0];
    float a = ldin(alpha, i, fl), b = ldin(betta, i, fl);
    float p0 = 1.f / (1.f + expf(-a));
    float p1 = (1.f - p0) / (1.f + expf(-b));
    float m = 2.f * p1 + p0 - 1.f;
    wmv[i] = m;
    wmv[n + i] = (1.f - p0) - m * m;
}

__global__ __launch_bounds__(256) void prep_w_r(
    const void* __restrict__ alpha, const void* __restrict__ betta,
    const int* __restrict__ flags, bf16* __restrict__ wmr, bf16* __restrict__ wvr,
    int CI, int n)
{
    int i = blockIdx.x * 256 + threadIdx.x;
    if (i >= n) return;
    int fl = flags[0];
    float a = ldin(alpha, i, fl), b = ldin(betta, i, fl);
    float p0 = 1.f / (1.f + expf(-a));
    float p1 = (1.f - p0) / (1.f + expf(-b));
    float m = 2.f * p1 + p0 - 1.f;
    float v = (1.f - p0) - m * m;
    int cirest = CI * 9;
    int co = i / cirest, rem = i % cirest;
    int ci = rem / 9, tap = rem % 9;
    int o = (co * 9 + tap) * CI + ci;
    wmr[o] = __float2bfloat16(m);
    wvr[o] = __float2bfloat16(v);
}

// ---------------------------------------------------------------------------
// fc1 weight permute via LDS tile transpose (coalesced both sides)
// ---------------------------------------------------------------------------
__global__ __launch_bounds__(256) void permute_fc1(
    const void* __restrict__ w, const int* __restrict__ flags, bf16* __restrict__ wp)
{
    __shared__ float L[8192];
    const int fl = flags[0];
    int tid = threadIdx.x;
    int o = blockIdx.x;
    size_t srow = (size_t)o * 8192;
    for (int c = tid; c < 512; c += 256) {
        float v[16];
        if (fl) {
            const uint4* s = (const uint4*)((const bf16*)w + srow + c * 16);
            uint4 u0 = s[0], u1 = s[1];
            const unsigned short* h0 = (const unsigned short*)&u0;
            const unsigned short* h1 = (const unsigned short*)&u1;
#pragma unroll
            for (int j = 0; j < 8; j++) { v[j] = b2f_bits((short)h0[j]); v[8 + j] = b2f_bits((short)h1[j]); }
        } else {
            const float4* s = (const float4*)((const float*)w + srow + c * 16);
#pragma unroll
            for (int j = 0; j < 4; j++) {
                float4 t4 = s[j];
                v[j * 4 + 0] = t4.x; v[j * 4 + 1] = t4.y; v[j * 4 + 2] = t4.z; v[j * 4 + 3] = t4.w;
            }
        }
#pragma unroll
        for (int hw = 0; hw < 16; hw++) L[hw * 512 + c] = v[hw];
    }
    __syncthreads();
    for (int j = 0; j < 32; j++) {
        int idx = j * 256 + tid;
        wp[srow + idx] = __float2bfloat16(L[idx]);
    }
}

// ---------------------------------------------------------------------------
// Layer 1 direct conv (CI=3). LDS-staged taps, coalesced NHWC bf16 writes.
// ---------------------------------------------------------------------------
__global__ __launch_bounds__(256) void l1_conv(
    const void* __restrict__ x, const float* __restrict__ wmv,
    const void* __restrict__ bias, const int* __restrict__ flags,
    bf16* __restrict__ out)
{
    __shared__ float Xs[64][28];
    const int fl = flags[0];
    int tid = threadIdx.x;
    int pos0 = blockIdx.x * 64;
    int b = pos0 >> 10;
    for (int u = tid; u < 576; u += 256) {
        int p = u / 9, r = u - p * 9;
        int ci = r / 3, kh = r - ci * 3;
        int pos = pos0 + p;
        int oh = (pos >> 5) & 31, ow = pos & 31;
        int ih = oh - 1 + kh;
        bool okh = (unsigned)ih < 32u;
        size_t base = ((size_t)(b * 3 + ci) * 32 + ih) * 32;
#pragma unroll
        for (int kw = 0; kw < 3; kw++) {
            int iw = ow - 1 + kw;
            float v = (okh && (unsigned)iw < 32u) ? ldin(x, base + iw, fl) : 0.f;
            Xs[p][ci * 9 + kh * 3 + kw] = v;
        }
    }
    int c = tid & 127, pg = tid >> 7;
    float wm[27], wv[27];
#pragma unroll
    for (int k = 0; k < 27; k++) {
        wm[k] = wmv[c * 27 + k];
        wv[k] = wmv[3456 + c * 27 + k];
    }
    float bs = ldin(bias, c, fl);
    __syncthreads();
    for (int it = 0; it < 32; it++) {
        int p = it * 2 + pg;
        float aM = 0.f, aV = 0.f;
#pragma unroll
        for (int k = 0; k < 27; k++) {
            float xv = Xs[p][k];
            aM = fmaf(xv, wm[k], aM);
            aV = fmaf(xv * xv, wv[k], aV);
        }
        out[(size_t)(pos0 + p) * 128 + c] =
            __float2bfloat16(erff((aM + bs) * rsqrtf(2.f * (aV + EPS))));
    }
}

// ---------------------------------------------------------------------------
// Implicit-GEMM LR-conv, bf16 MFMA 16x16x32, NHWC activations.
// ROUND-5 STRUCTURE, minimal occupancy diff: block tile 128pos x 64co,
// 4 waves in 2x2 over (pos-half 64, co-half 32). Per wave: accM[4][2] +
// accV[4][2] = 64 AGPR (half of round-5's 128). Plain launch bounds.
// ---------------------------------------------------------------------------
template<int CI, int CO, int H, int W, int S, int OH, int OW, int ACT>
__global__ __launch_bounds__(256) void conv_gemm(
    const bf16* __restrict__ xin,   // NHWC [B,H,W,CI]
    const bf16* __restrict__ wmr,   // [CO][9][CI]
    const bf16* __restrict__ wvr,
    const void* __restrict__ bias, const void* __restrict__ noise,
    const int* __restrict__ flags, void* __restrict__ outp)
{
    constexpr int OHW = OH * OW;
    __shared__ bf16 Xs[128 * 40];
    __shared__ bf16 Wms[64 * 40];
    __shared__ bf16 Wvs[64 * 40];

    int tid = threadIdx.x;
    int lane = tid & 63, wv_ = tid >> 6;
    int q = lane >> 4, l15 = lane & 15;
    const int pw = (wv_ >> 1) * 64, cw = (wv_ & 1) * 32;
    const int c0 = blockIdx.y * 64;

    // staging roles
    const int xrow_i = tid >> 1, xhalf = tid & 1;          // X: 128 rows, 32B halves
    const int wrow_i = (tid >> 1) & 63;                    // W: 64 rows x 2 paths, 32B halves
    const int wpath = tid >> 7, whalf = tid & 1;

    int P = blockIdx.x * 128 + xrow_i;
    int b = P / OHW, rr = P % OHW;
    int oh = rr / OW, owp = rr % OW;

    const bf16* wrow_base = (wpath ? wvr : wmr) + (size_t)(c0 + wrow_i) * 9 * CI;
    bf16* wdst = (wpath ? Wvs : Wms) + wrow_i * 40 + whalf * 16;

    f32x4 accM[4][2], accV[4][2];
#pragma unroll
    for (int i = 0; i < 4; i++)
#pragma unroll
        for (int j = 0; j < 2; j++) {
            accM[i][j] = (f32x4){0.f, 0.f, 0.f, 0.f};
            accV[i][j] = (f32x4){0.f, 0.f, 0.f, 0.f};
        }

    for (int kh = 0; kh < 3; kh++) {
        int ih = oh * S - 1 + kh;
        bool okh = (unsigned)ih < (unsigned)H;
        for (int kw = 0; kw < 3; kw++) {
            int iw = owp * S - 1 + kw;
            bool ok = okh && ((unsigned)iw < (unsigned)W);
            const bf16* xrow = xin + (((size_t)b * H + ih) * W + iw) * CI;
            const bf16* wrow = wrow_base + (kh * 3 + kw) * CI;
            for (int ci0 = 0; ci0 < CI; ci0 += 32) {
                __syncthreads();
                {   // stage X half-row (32 B)
                    uint4 v0 = {0, 0, 0, 0}, v1 = {0, 0, 0, 0};
                    if (ok) {
                        const uint4* s = (const uint4*)(xrow + ci0 + xhalf * 16);
                        v0 = s[0]; v1 = s[1];
                    }
                    uint4* d = (uint4*)(Xs + xrow_i * 40 + xhalf * 16);
                    d[0] = v0; d[1] = v1;
                }
                {   // stage W half-row (32 B), one path per thread-half
                    const uint4* s = (const uint4*)(wrow + ci0 + whalf * 16);
                    uint4* d = (uint4*)wdst;
                    d[0] = s[0]; d[1] = s[1];
                }
                __syncthreads();

                s16x8 a[4], a2[4], bm[2], bv[2];
#pragma unroll
                for (int i = 0; i < 4; i++) {
                    a[i]  = *(const s16x8*)(Xs + (pw + i * 16 + l15) * 40 + q * 8);
                    a2[i] = sq8(a[i]);
                }
#pragma unroll
                for (int j = 0; j < 2; j++) {
                    bm[j] = *(const s16x8*)(Wms + (cw + j * 16 + l15) * 40 + q * 8);
                    bv[j] = *(const s16x8*)(Wvs + (cw + j * 16 + l15) * 40 + q * 8);
                }
#pragma unroll
                for (int i = 0; i < 4; i++)
#pragma unroll
                    for (int j = 0; j < 2; j++) {
                        accM[i][j] = __builtin_amdgcn_mfma_f32_16x16x32_bf16(a[i],  bm[j], accM[i][j], 0, 0, 0);
                        accV[i][j] = __builtin_amdgcn_mfma_f32_16x16x32_bf16(a2[i], bv[j], accV[i][j], 0, 0, 0);
                    }
            }
        }
    }

    const int fl = flags[0];
#pragma unroll
    for (int j = 0; j < 2; j++) {
        int co = c0 + cw + j * 16 + l15;
        float bs = ldin(bias, co, fl);
#pragma unroll
        for (int i = 0; i < 4; i++) {
            f32x4 m4 = accM[i][j], v4 = accV[i][j];
#pragma unroll
            for (int r = 0; r < 4; r++) {
                int PP = blockIdx.x * 128 + pw + i * 16 + q * 4 + r;
                float mm = m4[r] + bs, vv = v4[r];
                if (ACT == 0) {
                    ((bf16*)outp)[(size_t)PP * CO + co] =
                        __float2bfloat16(erff(mm * rsqrtf(2.f * (vv + EPS))));
                } else {
                    int bb = PP / OHW, hw = PP % OHW;
                    float nz = ldin(noise, ((size_t)bb * CO + co) * OHW + hw, fl);
                    ((float*)outp)[(size_t)PP * CO + co] = mm + sqrtf(vv + EPS) * nz;
                }
            }
        }
    }
}

// ---------------------------------------------------------------------------
// FC1 split-K MFMA GEMM: partial[ks][256][1024] over K-slice of 1024
// ---------------------------------------------------------------------------
__global__ __launch_bounds__(256) void fc1_gemm_sk(
    const bf16* __restrict__ A, const bf16* __restrict__ Wp,
    float* __restrict__ part)
{
    __shared__ bf16 Xs[128 * 40];
    __shared__ bf16 Ws[128 * 40];
    int tid = threadIdx.x;
    int lane = tid & 63, wv_ = tid >> 6;
    int q = lane >> 4, l15 = lane & 15;
    const int pw = (wv_ >> 1) * 64, cw = (wv_ & 1) * 64;
    const int p0 = blockIdx.x * 128, c0 = blockIdx.y * 128;
    const int kb = blockIdx.z * 1024;
    const int row_i = tid >> 1, half = tid & 1;

    f32x4 acc[4][4];
#pragma unroll
    for (int i = 0; i < 4; i++)
#pragma unroll
        for (int j = 0; j < 4; j++) acc[i][j] = (f32x4){0.f, 0.f, 0.f, 0.f};

    for (int k0 = kb; k0 < kb + 1024; k0 += 32) {
        __syncthreads();
        {
            const uint4* s = (const uint4*)(A + (size_t)(p0 + row_i) * 8192 + k0 + half * 16);
            uint4* d = (uint4*)(Xs + row_i * 40 + half * 16);
            d[0] = s[0]; d[1] = s[1];
        }
        {
            const uint4* s = (const uint4*)(Wp + (size_t)(c0 + row_i) * 8192 + k0 + half * 16);
            uint4* d = (uint4*)(Ws + row_i * 40 + half * 16);
            d[0] = s[0]; d[1] = s[1];
        }
        __syncthreads();
        s16x8 a[4], bb[4];
#pragma unroll
        for (int i = 0; i < 4; i++) {
            a[i]  = *(const s16x8*)(Xs + (pw + i * 16 + l15) * 40 + q * 8);
            bb[i] = *(const s16x8*)(Ws + (cw + i * 16 + l15) * 40 + q * 8);
        }
#pragma unroll
        for (int i = 0; i < 4; i++)
#pragma unroll
            for (int j = 0; j < 4; j++)
                acc[i][j] = __builtin_amdgcn_mfma_f32_16x16x32_bf16(a[i], bb[j], acc[i][j], 0, 0, 0);
    }

    float* pbase = part + (size_t)blockIdx.z * 256 * 1024;
#pragma unroll
    for (int j = 0; j < 4; j++) {
        int co = c0 + cw + j * 16 + l15;
#pragma unroll
        for (int i = 0; i < 4; i++) {
            f32x4 m4 = acc[i][j];
#pragma unroll
            for (int r = 0; r < 4; r++) {
                int P = p0 + pw + i * 16 + q * 4 + r;
                pbase[(size_t)P * 1024 + co] = m4[r];
            }
        }
    }
}

__global__ __launch_bounds__(256) void fc1_reduce(
    const float* __restrict__ part, const void* __restrict__ bias,
    const int* __restrict__ flags, float* __restrict__ out)
{
    int i = blockIdx.x * 256 + threadIdx.x;  // 262144
    float s = 0.f;
#pragma unroll
    for (int k = 0; k < 8; k++) s += part[(size_t)k * 262144 + i];
    out[i] = fmaxf(s + ldin(bias, i & 1023, flags[0]), 0.f);
}

// ---------------------------------------------------------------------------
// BatchNorm over NHWC z [4096 pos][512 c]
// ---------------------------------------------------------------------------
__global__ __launch_bounds__(256) void bn_part(const float* __restrict__ z,
                                               float4* __restrict__ partial)
{
    int blk = blockIdx.x;  // 128
    int t = threadIdx.x;
    float s0 = 0, ss0 = 0, s1 = 0, ss1 = 0;
    for (int p = 0; p < 32; p++) {
        float2 v = ((const float2*)z)[((size_t)(blk * 32 + p)) * 256 + t];
        s0 += v.x; ss0 += v.x * v.x;
        s1 += v.y; ss1 += v.y * v.y;
    }
    partial[blk * 256 + t] = make_float4(s0, ss0, s1, ss1);
}

__global__ __launch_bounds__(512) void bn_fin(
    const float4* __restrict__ partial, const void* __restrict__ gamma,
    const void* __restrict__ beta, const int* __restrict__ flags,
    float* __restrict__ sc, float* __restrict__ sh)
{
    int c = threadIdx.x;  // 512
    float s = 0, ss = 0;
    for (int j = 0; j < 128; j++) {
        float4 pv = partial[j * 256 + (c >> 1)];
        s += (c & 1) ? pv.z : pv.x;
        ss += (c & 1) ? pv.w : pv.y;
    }
    float mean = s * (1.f / 4096.f);
    float var = ss * (1.f / 4096.f) - mean * mean;
    int fl = flags[0];
    float scale = ldin(gamma, c, fl) * rsqrtf(var + EPS);
    sc[c] = scale;
    sh[c] = ldin(beta, c, fl) - mean * scale;
}

__global__ __launch_bounds__(256) void bn_apply(
    const float* __restrict__ z, const float* __restrict__ sc,
    const float* __restrict__ sh, bf16* __restrict__ zr)
{
    int i = blockIdx.x * 256 + threadIdx.x;  // 2097152
    int c = i & 511;
    float v = z[i] * sc[c] + sh[c];
    zr[i] = __float2bfloat16(fmaxf(v, 0.f));
}

// ---------------------------------------------------------------------------
// FC2: out[256,10] = fc1o @ W^T + b
// ---------------------------------------------------------------------------
__global__ __launch_bounds__(640) void fc2_kernel(
    const float* __restrict__ A, const void* __restrict__ W,
    const void* __restrict__ bias, const int* __restrict__ flags,
    void* __restrict__ out)
{
    const int fl = flags[0];
    int n = blockIdx.x;
    int o = threadIdx.x >> 6;  // 0..9
    int lane = threadIdx.x & 63;
    const float* a = A + (size_t)n * 1024;
    size_t wbase = (size_t)o * 1024;
    float s = 0.f;
    for (int i = lane; i < 1024; i += 64) s = fmaf(a[i], ldin(W, wbase + i, fl), s);
#pragma unroll
    for (int off = 32; off > 0; off >>= 1) s += __shfl_down(s, off);
    if (lane == 0) {
        float v = s + ldin(bias, o, fl);
        if (fl) ((bf16*)out)[n * 10 + o] = __float2bfloat16(v);
        else    ((float*)out)[n * 10 + o] = v;
    }
}

// ---------------------------------------------------------------------------
extern "C" void kernel_launch(void* const* d_in, const int* in_sizes, int n_in,
                              void* d_out, int out_size, void* d_ws, size_t ws_size,
                              hipStream_t stream)
{
    const void* x = d_in[0];
    const void *al[6], *be[6], *bi[6];
    for (int l = 0; l < 6; l++) {
        al[l] = d_in[1 + 3 * l];
        be[l] = d_in[2 + 3 * l];
        bi[l] = d_in[3 + 3 * l];
    }
    const void* bn_gamma = d_in[19];
    const void* bn_beta  = d_in[20];
    const void* fc1_w = d_in[21];
    const void* fc1_b = d_in[22];
    const void* fc2_w = d_in[23];
    const void* fc2_b = d_in[24];
    const void* noise = d_in[25];

    // ---- workspace (~134 MB) ----
    char* base = (char*)d_ws;
    size_t off = 0;
    auto alloc = [&](size_t bytes) { void* p = base + off; off += (bytes + 255) & ~(size_t)255; return p; };
    int* flags = (int*)alloc(256);
    float* w1 = (float*)alloc(2 * 3456 * sizeof(float));
    const int SwCI[5] = {128, 128, 256, 256, 512};
    const size_t Sw[5] = {147456, 294912, 589824, 1179648, 2359296};
    bf16 *wmr[5], *wvr[5];
    for (int l = 0; l < 5; l++) {
        wmr[l] = (bf16*)alloc(Sw[l] * sizeof(bf16));
        wvr[l] = (bf16*)alloc(Sw[l] * sizeof(bf16));
    }
    bf16* actA = (bf16*)alloc((size_t)256 * 1024 * 128 * sizeof(bf16));  // 67 MB
    bf16* actB = (bf16*)alloc((size_t)256 * 256 * 128 * sizeof(bf16));   // 16.8 MB
    float* z   = (float*)alloc((size_t)4096 * 512 * sizeof(float));      // 8.4 MB
    bf16* zr   = (bf16*)alloc((size_t)256 * 8192 * sizeof(bf16));        // 4.2 MB
    bf16* Wp   = (bf16*)alloc((size_t)1024 * 8192 * sizeof(bf16));       // 16.8 MB
    float4* part = (float4*)alloc((size_t)128 * 256 * sizeof(float4));   // 0.5 MB
    float* bnsc = (float*)alloc(512 * sizeof(float));
    float* bnsh = (float*)alloc(512 * sizeof(float));
    float* fc1o = (float*)alloc((size_t)256 * 1024 * sizeof(float));     // 1 MB
    // fc1 split-K partials reuse actB (free after conv layer 6): 8.4 MB f32
    float* fc1part = (float*)actB;

    detect_kernel<<<1, 64, 0, stream>>>(x, flags);

    prep_w_l1<<<14, 256, 0, stream>>>(al[0], be[0], flags, w1, 3456);
    for (int l = 0; l < 5; l++) {
        int n = (int)Sw[l];
        prep_w_r<<<(n + 255) / 256, 256, 0, stream>>>(
            al[l + 1], be[l + 1], flags, wmr[l], wvr[l], SwCI[l], n);
    }
    permute_fc1<<<1024, 256, 0, stream>>>(fc1_w, flags, Wp);

    // layer 1: direct, NHWC bf16 out, coalesced
    l1_conv<<<4096, 256, 0, stream>>>(x, w1, bi[0], flags, actA);

    // layers 2..6: implicit-GEMM MFMA, 128x64 block tile (64 AGPR/wave)
    conv_gemm<128, 128, 32, 32, 2, 16, 16, 0><<<dim3(512, 2), 256, 0, stream>>>(
        actA, wmr[0], wvr[0], bi[1], nullptr, flags, actB);
    conv_gemm<128, 256, 16, 16, 1, 16, 16, 0><<<dim3(512, 4), 256, 0, stream>>>(
        actB, wmr[1], wvr[1], bi[2], nullptr, flags, actA);
    conv_gemm<256, 256, 16, 16, 2, 8, 8, 0><<<dim3(128, 4), 256, 0, stream>>>(
        actA, wmr[2], wvr[2], bi[3], nullptr, flags, actB);
    conv_gemm<256, 512, 8, 8, 1, 8, 8, 0><<<dim3(128, 8), 256, 0, stream>>>(
        actB, wmr[3], wvr[3], bi[4], nullptr, flags, actA);
    conv_gemm<512, 512, 8, 8, 2, 4, 4, 1><<<dim3(32, 8), 256, 0, stream>>>(
        actA, wmr[4], wvr[4], bi[5], noise, flags, z);

    // batchnorm + relu (NHWC == fc1 k' order)
    bn_part<<<128, 256, 0, stream>>>(z, part);
    bn_fin<<<1, 512, 0, stream>>>(part, bn_gamma, bn_beta, flags, bnsc, bnsh);
    bn_apply<<<8192, 256, 0, stream>>>(z, bnsc, bnsh, zr);

    // classifier head (split-K x8 into fc1part, then reduce+bias+relu)
    fc1_gemm_sk<<<dim3(2, 8, 8), 256, 0, stream>>>(zr, Wp, fc1part);
    fc1_reduce<<<1024, 256, 0, stream>>>(fc1part, fc1_b, flags, fc1o);
    fc2_kernel<<<256, 640, 0, stream>>>(fc1o, fc2_w, fc2_b, flags, d_out);
}

// Round 10
// 854.028 us; speedup vs baseline: 7.9301x; 1.0795x over previous
//
#include <hip/hip_runtime.h>
#include <hip/hip_bf16.h>
#include <math.h>

#define EPS 1e-5f

typedef __hip_bfloat16 bf16;
typedef short s16x8 __attribute__((ext_vector_type(8)));
typedef float f32x4 __attribute__((ext_vector_type(4)));

__device__ __forceinline__ float bf2f(bf16 v) { return __bfloat162float(v); }
__device__ __forceinline__ float ldin(const void* p, size_t i, int isbf) {
    return isbf ? __bfloat162float(((const bf16*)p)[i]) : ((const float*)p)[i];
}
__device__ __forceinline__ float b2f_bits(short s) {
    unsigned u = ((unsigned)(unsigned short)s) << 16;
    return __builtin_bit_cast(float, u);
}
// packed square of 2 bf16 per uint, round-half-up (x^2 >= 0, inputs |x|<~30)
__device__ __forceinline__ uint4 sqpk4(uint4 u) {
    uint4 r;
    unsigned* up = (unsigned*)&u;
    unsigned* rp = (unsigned*)&r;
#pragma unroll
    for (int k = 0; k < 4; k++) {
        unsigned w = up[k];
        float lo = __builtin_bit_cast(float, w << 16);
        float hi = __builtin_bit_cast(float, w & 0xffff0000u);
        lo *= lo; hi *= hi;
        unsigned ul = __builtin_bit_cast(unsigned, lo) + 0x8000u;
        unsigned uh = __builtin_bit_cast(unsigned, hi) + 0x8000u;
        rp[k] = (ul >> 16) | (uh & 0xffff0000u);
    }
    return r;
}

// ---------------------------------------------------------------------------
// dtype sniff (f32 vs bf16-packed inputs); flags[0]=1 => bf16
// ---------------------------------------------------------------------------
__global__ __launch_bounds__(64) void detect_kernel(const void* __restrict__ x,
                                                    int* __restrict__ flags) {
    const unsigned* w = (const unsigned*)x;
    unsigned word = w[threadIdx.x];
    int e = (word >> 23) & 0xFF;
    bool ok = (word == 0u) || (e >= 0x70 && e <= 0x8E);
    unsigned long long m = __ballot(ok);
    if (threadIdx.x == 0) flags[0] = (__popcll(m) >= 32) ? 0 : 1;
}

// ---------------------------------------------------------------------------
// Ternary-weight prep. L1: f32 natural [co][ci][3][3]; GEMM: bf16 [co][tap][ci]
// ---------------------------------------------------------------------------
__global__ __launch_bounds__(256) void prep_w_l1(
    const void* __restrict__ alpha, const void* __restrict__ betta,
    const int* __restrict__ flags, float* __restrict__ wmv, int n)
{
    int i = blockIdx.x * 256 + threadIdx.x;
    if (i >= n) return;
    int fl = flags[0];
    float a = ldin(alpha, i, fl), b = ldin(betta, i, fl);
    float p0 = 1.f / (1.f + expf(-a));
    float p1 = (1.f - p0) / (1.f + expf(-b));
    float m = 2.f * p1 + p0 - 1.f;
    wmv[i] = m;
    wmv[n + i] = (1.f - p0) - m * m;
}

__global__ __launch_bounds__(256) void prep_w_r(
    const void* __restrict__ alpha, const void* __restrict__ betta,
    const int* __restrict__ flags, bf16* __restrict__ wmr, bf16* __restrict__ wvr,
    int CI, int n)
{
    int i = blockIdx.x * 256 + threadIdx.x;
    if (i >= n) return;
    int fl = flags[0];
    float a = ldin(alpha, i, fl), b = ldin(betta, i, fl);
    float p0 = 1.f / (1.f + expf(-a));
    float p1 = (1.f - p0) / (1.f + expf(-b));
    float m = 2.f * p1 + p0 - 1.f;
    float v = (1.f - p0) - m * m;
    int cirest = CI * 9;
    int co = i / cirest, rem = i % cirest;
    int ci = rem / 9, tap = rem % 9;
    int o = (co * 9 + tap) * CI + ci;
    wmr[o] = __float2bfloat16(m);
    wvr[o] = __float2bfloat16(v);
}

// ---------------------------------------------------------------------------
// fc1 weight permute via LDS tile transpose (coalesced both sides)
// ---------------------------------------------------------------------------
__global__ __launch_bounds__(256) void permute_fc1(
    const void* __restrict__ w, const int* __restrict__ flags, bf16* __restrict__ wp)
{
    __shared__ float L[8192];
    const int fl = flags[0];
    int tid = threadIdx.x;
    int o = blockIdx.x;
    size_t srow = (size_t)o * 8192;
    for (int c = tid; c < 512; c += 256) {
        float v[16];
        if (fl) {
            const uint4* s = (const uint4*)((const bf16*)w + srow + c * 16);
            uint4 u0 = s[0], u1 = s[1];
            const unsigned short* h0 = (const unsigned short*)&u0;
            const unsigned short* h1 = (const unsigned short*)&u1;
#pragma unroll
            for (int j = 0; j < 8; j++) { v[j] = b2f_bits((short)h0[j]); v[8 + j] = b2f_bits((short)h1[j]); }
        } else {
            const float4* s = (const float4*)((const float*)w + srow + c * 16);
#pragma unroll
            for (int j = 0; j < 4; j++) {
                float4 t4 = s[j];
                v[j * 4 + 0] = t4.x; v[j * 4 + 1] = t4.y; v[j * 4 + 2] = t4.z; v[j * 4 + 3] = t4.w;
            }
        }
#pragma unroll
        for (int hw = 0; hw < 16; hw++) L[hw * 512 + c] = v[hw];
    }
    __syncthreads();
    for (int j = 0; j < 32; j++) {
        int idx = j * 256 + tid;
        wp[srow + idx] = __float2bfloat16(L[idx]);
    }
}

// ---------------------------------------------------------------------------
// Layer 1 direct conv (CI=3). LDS-staged taps, coalesced NHWC bf16 writes.
// ---------------------------------------------------------------------------
__global__ __launch_bounds__(256) void l1_conv(
    const void* __restrict__ x, const float* __restrict__ wmv,
    const void* __restrict__ bias, const int* __restrict__ flags,
    bf16* __restrict__ out)
{
    __shared__ float Xs[64][28];
    const int fl = flags[0];
    int tid = threadIdx.x;
    int pos0 = blockIdx.x * 64;
    int b = pos0 >> 10;
    for (int u = tid; u < 576; u += 256) {
        int p = u / 9, r = u - p * 9;
        int ci = r / 3, kh = r - ci * 3;
        int pos = pos0 + p;
        int oh = (pos >> 5) & 31, ow = pos & 31;
        int ih = oh - 1 + kh;
        bool okh = (unsigned)ih < 32u;
        size_t base = ((size_t)(b * 3 + ci) * 32 + ih) * 32;
#pragma unroll
        for (int kw = 0; kw < 3; kw++) {
            int iw = ow - 1 + kw;
            float v = (okh && (unsigned)iw < 32u) ? ldin(x, base + iw, fl) : 0.f;
            Xs[p][ci * 9 + kh * 3 + kw] = v;
        }
    }
    int c = tid & 127, pg = tid >> 7;
    float wm[27], wv[27];
#pragma unroll
    for (int k = 0; k < 27; k++) {
        wm[k] = wmv[c * 27 + k];
        wv[k] = wmv[3456 + c * 27 + k];
    }
    float bs = ldin(bias, c, fl);
    __syncthreads();
    for (int it = 0; it < 32; it++) {
        int p = it * 2 + pg;
        float aM = 0.f, aV = 0.f;
#pragma unroll
        for (int k = 0; k < 27; k++) {
            float xv = Xs[p][k];
            aM = fmaf(xv, wm[k], aM);
            aV = fmaf(xv * xv, wv[k], aV);
        }
        out[(size_t)(pos0 + p) * 128 + c] =
            __float2bfloat16(erff((aM + bs) * rsqrtf(2.f * (aV + EPS))));
    }
}

// ---------------------------------------------------------------------------
// Implicit-GEMM LR-conv, bf16 MFMA 16x16x32, NHWC activations.
// Block tile 128pos x 64co, K-chunk 64, X^2 staged in LDS (no inner-loop
// squaring VALU). Per wave: accM[4][2]+accV[4][2] = 64 AGPR.
// ---------------------------------------------------------------------------
template<int CI, int CO, int H, int W, int S, int OH, int OW, int ACT>
__global__ __launch_bounds__(256) void conv_gemm(
    const bf16* __restrict__ xin,   // NHWC [B,H,W,CI]
    const bf16* __restrict__ wmr,   // [CO][9][CI]
    const bf16* __restrict__ wvr,
    const void* __restrict__ bias, const void* __restrict__ noise,
    const int* __restrict__ flags, void* __restrict__ outp)
{
    constexpr int OHW = OH * OW;
    constexpr int RL = 72;          // row length bf16: 64 K-elems + 8 pad (144 B)
    __shared__ bf16 Xs [128 * RL];
    __shared__ bf16 Xq [128 * RL];  // squared copy
    __shared__ bf16 Wms[64 * RL];
    __shared__ bf16 Wvs[64 * RL];

    int tid = threadIdx.x;
    int lane = tid & 63, wv_ = tid >> 6;
    int q = lane >> 4, l15 = lane & 15;
    const int pw = (wv_ >> 1) * 64, cw = (wv_ & 1) * 32;
    const int c0 = blockIdx.y * 64;

    // staging roles
    const int xrow_i = tid >> 1, xhalf = tid & 1;          // X: 128 rows, 64B halves
    const int wrow_i = (tid >> 1) & 63;                    // W: 64 rows x 2 paths
    const int wpath = tid >> 7, whalf = tid & 1;

    int P = blockIdx.x * 128 + xrow_i;
    int b = P / OHW, rr = P % OHW;
    int oh = rr / OW, owp = rr % OW;

    const bf16* wrow_base = (wpath ? wvr : wmr) + (size_t)(c0 + wrow_i) * 9 * CI;
    bf16* wdst = (wpath ? Wvs : Wms) + wrow_i * RL + whalf * 32;

    f32x4 accM[4][2], accV[4][2];
#pragma unroll
    for (int i = 0; i < 4; i++)
#pragma unroll
        for (int j = 0; j < 2; j++) {
            accM[i][j] = (f32x4){0.f, 0.f, 0.f, 0.f};
            accV[i][j] = (f32x4){0.f, 0.f, 0.f, 0.f};
        }

    for (int kh = 0; kh < 3; kh++) {
        int ih = oh * S - 1 + kh;
        bool okh = (unsigned)ih < (unsigned)H;
        for (int kw = 0; kw < 3; kw++) {
            int iw = owp * S - 1 + kw;
            bool ok = okh && ((unsigned)iw < (unsigned)W);
            const bf16* xrow = xin + (((size_t)b * H + ih) * W + iw) * CI;
            const bf16* wrow = wrow_base + (kh * 3 + kw) * CI;
            for (int ci0 = 0; ci0 < CI; ci0 += 64) {
                __syncthreads();
                {   // stage X 64B half-row + squared copy
                    uint4 v[4];
#pragma unroll
                    for (int k = 0; k < 4; k++) v[k] = (uint4){0, 0, 0, 0};
                    if (ok) {
                        const uint4* s = (const uint4*)(xrow + ci0 + xhalf * 32);
#pragma unroll
                        for (int k = 0; k < 4; k++) v[k] = s[k];
                    }
                    uint4* d  = (uint4*)(Xs + xrow_i * RL + xhalf * 32);
                    uint4* d2 = (uint4*)(Xq + xrow_i * RL + xhalf * 32);
#pragma unroll
                    for (int k = 0; k < 4; k++) { d[k] = v[k]; d2[k] = sqpk4(v[k]); }
                }
                {   // stage W 64B half-row, one path per thread-half
                    const uint4* s = (const uint4*)(wrow + ci0 + whalf * 32);
                    uint4* d = (uint4*)wdst;
#pragma unroll
                    for (int k = 0; k < 4; k++) d[k] = s[k];
                }
                __syncthreads();

#pragma unroll
                for (int ks = 0; ks < 2; ks++) {
                    s16x8 a[4], a2[4], bm[2], bv[2];
#pragma unroll
                    for (int i = 0; i < 4; i++) {
                        a[i]  = *(const s16x8*)(Xs + (pw + i * 16 + l15) * RL + ks * 32 + q * 8);
                        a2[i] = *(const s16x8*)(Xq + (pw + i * 16 + l15) * RL + ks * 32 + q * 8);
                    }
#pragma unroll
                    for (int j = 0; j < 2; j++) {
                        bm[j] = *(const s16x8*)(Wms + (cw + j * 16 + l15) * RL + ks * 32 + q * 8);
                        bv[j] = *(const s16x8*)(Wvs + (cw + j * 16 + l15) * RL + ks * 32 + q * 8);
                    }
#pragma unroll
                    for (int i = 0; i < 4; i++)
#pragma unroll
                        for (int j = 0; j < 2; j++) {
                            accM[i][j] = __builtin_amdgcn_mfma_f32_16x16x32_bf16(a[i],  bm[j], accM[i][j], 0, 0, 0);
                            accV[i][j] = __builtin_amdgcn_mfma_f32_16x16x32_bf16(a2[i], bv[j], accV[i][j], 0, 0, 0);
                        }
                }
            }
        }
    }

    const int fl = flags[0];
#pragma unroll
    for (int j = 0; j < 2; j++) {
        int co = c0 + cw + j * 16 + l15;
        float bs = ldin(bias, co, fl);
#pragma unroll
        for (int i = 0; i < 4; i++) {
            f32x4 m4 = accM[i][j], v4 = accV[i][j];
#pragma unroll
            for (int r = 0; r < 4; r++) {
                int PP = blockIdx.x * 128 + pw + i * 16 + q * 4 + r;
                float mm = m4[r] + bs, vv = v4[r];
                if (ACT == 0) {
                    ((bf16*)outp)[(size_t)PP * CO + co] =
                        __float2bfloat16(erff(mm * rsqrtf(2.f * (vv + EPS))));
                } else {
                    int bb = PP / OHW, hw = PP % OHW;
                    float nz = ldin(noise, ((size_t)bb * CO + co) * OHW + hw, fl);
                    ((float*)outp)[(size_t)PP * CO + co] = mm + sqrtf(vv + EPS) * nz;
                }
            }
        }
    }
}

// ---------------------------------------------------------------------------
// FC1 split-K MFMA GEMM: partial[ks][256][1024] over K-slice of 1024
// ---------------------------------------------------------------------------
__global__ __launch_bounds__(256) void fc1_gemm_sk(
    const bf16* __restrict__ A, const bf16* __restrict__ Wp,
    float* __restrict__ part)
{
    __shared__ bf16 Xs[128 * 40];
    __shared__ bf16 Ws[128 * 40];
    int tid = threadIdx.x;
    int lane = tid & 63, wv_ = tid >> 6;
    int q = lane >> 4, l15 = lane & 15;
    const int pw = (wv_ >> 1) * 64, cw = (wv_ & 1) * 64;
    const int p0 = blockIdx.x * 128, c0 = blockIdx.y * 128;
    const int kb = blockIdx.z * 1024;
    const int row_i = tid >> 1, half = tid & 1;

    f32x4 acc[4][4];
#pragma unroll
    for (int i = 0; i < 4; i++)
#pragma unroll
        for (int j = 0; j < 4; j++) acc[i][j] = (f32x4){0.f, 0.f, 0.f, 0.f};

    for (int k0 = kb; k0 < kb + 1024; k0 += 32) {
        __syncthreads();
        {
            const uint4* s = (const uint4*)(A + (size_t)(p0 + row_i) * 8192 + k0 + half * 16);
            uint4* d = (uint4*)(Xs + row_i * 40 + half * 16);
            d[0] = s[0]; d[1] = s[1];
        }
        {
            const uint4* s = (const uint4*)(Wp + (size_t)(c0 + row_i) * 8192 + k0 + half * 16);
            uint4* d = (uint4*)(Ws + row_i * 40 + half * 16);
            d[0] = s[0]; d[1] = s[1];
        }
        __syncthreads();
        s16x8 a[4], bb[4];
#pragma unroll
        for (int i = 0; i < 4; i++) {
            a[i]  = *(const s16x8*)(Xs + (pw + i * 16 + l15) * 40 + q * 8);
            bb[i] = *(const s16x8*)(Ws + (cw + i * 16 + l15) * 40 + q * 8);
        }
#pragma unroll
        for (int i = 0; i < 4; i++)
#pragma unroll
            for (int j = 0; j < 4; j++)
                acc[i][j] = __builtin_amdgcn_mfma_f32_16x16x32_bf16(a[i], bb[j], acc[i][j], 0, 0, 0);
    }

    float* pbase = part + (size_t)blockIdx.z * 256 * 1024;
#pragma unroll
    for (int j = 0; j < 4; j++) {
        int co = c0 + cw + j * 16 + l15;
#pragma unroll
        for (int i = 0; i < 4; i++) {
            f32x4 m4 = acc[i][j];
#pragma unroll
            for (int r = 0; r < 4; r++) {
                int P = p0 + pw + i * 16 + q * 4 + r;
                pbase[(size_t)P * 1024 + co] = m4[r];
            }
        }
    }
}

__global__ __launch_bounds__(256) void fc1_reduce(
    const float* __restrict__ part, const void* __restrict__ bias,
    const int* __restrict__ flags, float* __restrict__ out)
{
    int i = blockIdx.x * 256 + threadIdx.x;  // 262144
    float s = 0.f;
#pragma unroll
    for (int k = 0; k < 8; k++) s += part[(size_t)k * 262144 + i];
    out[i] = fmaxf(s + ldin(bias, i & 1023, flags[0]), 0.f);
}

// ---------------------------------------------------------------------------
// BatchNorm over NHWC z [4096 pos][512 c]
// ---------------------------------------------------------------------------
__global__ __launch_bounds__(256) void bn_part(const float* __restrict__ z,
                                               float4* __restrict__ partial)
{
    int blk = blockIdx.x;  // 128
    int t = threadIdx.x;
    float s0 = 0, ss0 = 0, s1 = 0, ss1 = 0;
    for (int p = 0; p < 32; p++) {
        float2 v = ((const float2*)z)[((size_t)(blk * 32 + p)) * 256 + t];
        s0 += v.x; ss0 += v.x * v.x;
        s1 += v.y; ss1 += v.y * v.y;
    }
    partial[blk * 256 + t] = make_float4(s0, ss0, s1, ss1);
}

__global__ __launch_bounds__(512) void bn_fin(
    const float4* __restrict__ partial, const void* __restrict__ gamma,
    const void* __restrict__ beta, const int* __restrict__ flags,
    float* __restrict__ sc, float* __restrict__ sh)
{
    int c = threadIdx.x;  // 512
    float s = 0, ss = 0;
    for (int j = 0; j < 128; j++) {
        float4 pv = partial[j * 256 + (c >> 1)];
        s += (c & 1) ? pv.z : pv.x;
        ss += (c & 1) ? pv.w : pv.y;
    }
    float mean = s * (1.f / 4096.f);
    float var = ss * (1.f / 4096.f) - mean * mean;
    int fl = flags[0];
    float scale = ldin(gamma, c, fl) * rsqrtf(var + EPS);
    sc[c] = scale;
    sh[c] = ldin(beta, c, fl) - mean * scale;
}

__global__ __launch_bounds__(256) void bn_apply(
    const float* __restrict__ z, const float* __restrict__ sc,
    const float* __restrict__ sh, bf16* __restrict__ zr)
{
    int i = blockIdx.x * 256 + threadIdx.x;  // 2097152
    int c = i & 511;
    float v = z[i] * sc[c] + sh[c];
    zr[i] = __float2bfloat16(fmaxf(v, 0.f));
}

// ---------------------------------------------------------------------------
// FC2: out[256,10] = fc1o @ W^T + b
// ---------------------------------------------------------------------------
__global__ __launch_bounds__(640) void fc2_kernel(
    const float* __restrict__ A, const void* __restrict__ W,
    const void* __restrict__ bias, const int* __restrict__ flags,
    void* __restrict__ out)
{
    const int fl = flags[0];
    int n = blockIdx.x;
    int o = threadIdx.x >> 6;  // 0..9
    int lane = threadIdx.x & 63;
    const float* a = A + (size_t)n * 1024;
    size_t wbase = (size_t)o * 1024;
    float s = 0.f;
    for (int i = lane; i < 1024; i += 64) s = fmaf(a[i], ldin(W, wbase + i, fl), s);
#pragma unroll
    for (int off = 32; off > 0; off >>= 1) s += __shfl_down(s, off);
    if (lane == 0) {
        float v = s + ldin(bias, o, fl);
        if (fl) ((bf16*)out)[n * 10 + o] = __float2bfloat16(v);
        else    ((float*)out)[n * 10 + o] = v;
    }
}

// ---------------------------------------------------------------------------
extern "C" void kernel_launch(void* const* d_in, const int* in_sizes, int n_in,
                              void* d_out, int out_size, void* d_ws, size_t ws_size,
                              hipStream_t stream)
{
    const void* x = d_in[0];
    const void *al[6], *be[6], *bi[6];
    for (int l = 0; l < 6; l++) {
        al[l] = d_in[1 + 3 * l];
        be[l] = d_in[2 + 3 * l];
        bi[l] = d_in[3 + 3 * l];
    }
    const void* bn_gamma = d_in[19];
    const void* bn_beta  = d_in[20];
    const void* fc1_w = d_in[21];
    const void* fc1_b = d_in[22];
    const void* fc2_w = d_in[23];
    const void* fc2_b = d_in[24];
    const void* noise = d_in[25];

    // ---- workspace (~134 MB) ----
    char* base = (char*)d_ws;
    size_t off = 0;
    auto alloc = [&](size_t bytes) { void* p = base + off; off += (bytes + 255) & ~(size_t)255; return p; };
    int* flags = (int*)alloc(256);
    float* w1 = (float*)alloc(2 * 3456 * sizeof(float));
    const int SwCI[5] = {128, 128, 256, 256, 512};
    const size_t Sw[5] = {147456, 294912, 589824, 1179648, 2359296};
    bf16 *wmr[5], *wvr[5];
    for (int l = 0; l < 5; l++) {
        wmr[l] = (bf16*)alloc(Sw[l] * sizeof(bf16));
        wvr[l] = (bf16*)alloc(Sw[l] * sizeof(bf16));
    }
    bf16* actA = (bf16*)alloc((size_t)256 * 1024 * 128 * sizeof(bf16));  // 67 MB
    bf16* actB = (bf16*)alloc((size_t)256 * 256 * 128 * sizeof(bf16));   // 16.8 MB
    float* z   = (float*)alloc((size_t)4096 * 512 * sizeof(float));      // 8.4 MB
    bf16* zr   = (bf16*)alloc((size_t)256 * 8192 * sizeof(bf16));        // 4.2 MB
    bf16* Wp   = (bf16*)alloc((size_t)1024 * 8192 * sizeof(bf16));       // 16.8 MB
    float4* part = (float4*)alloc((size_t)128 * 256 * sizeof(float4));   // 0.5 MB
    float* bnsc = (float*)alloc(512 * sizeof(float));
    float* bnsh = (float*)alloc(512 * sizeof(float));
    float* fc1o = (float*)alloc((size_t)256 * 1024 * sizeof(float));     // 1 MB
    // fc1 split-K partials reuse actB (free after conv layer 6): 8.4 MB f32
    float* fc1part = (float*)actB;

    detect_kernel<<<1, 64, 0, stream>>>(x, flags);

    prep_w_l1<<<14, 256, 0, stream>>>(al[0], be[0], flags, w1, 3456);
    for (int l = 0; l < 5; l++) {
        int n = (int)Sw[l];
        prep_w_r<<<(n + 255) / 256, 256, 0, stream>>>(
            al[l + 1], be[l + 1], flags, wmr[l], wvr[l], SwCI[l], n);
    }
    permute_fc1<<<1024, 256, 0, stream>>>(fc1_w, flags, Wp);

    // layer 1: direct, NHWC bf16 out, coalesced
    l1_conv<<<4096, 256, 0, stream>>>(x, w1, bi[0], flags, actA);

    // layers 2..6: implicit-GEMM MFMA, 128x64 tile, K64 chunks, staged X^2
    conv_gemm<128, 128, 32, 32, 2, 16, 16, 0><<<dim3(512, 2), 256, 0, stream>>>(
        actA, wmr[0], wvr[0], bi[1], nullptr, flags, actB);
    conv_gemm<128, 256, 16, 16, 1, 16, 16, 0><<<dim3(512, 4), 256, 0, stream>>>(
        actB, wmr[1], wvr[1], bi[2], nullptr, flags, actA);
    conv_gemm<256, 256, 16, 16, 2, 8, 8, 0><<<dim3(128, 4), 256, 0, stream>>>(
        actA, wmr[2], wvr[2], bi[3], nullptr, flags, actB);
    conv_gemm<256, 512, 8, 8, 1, 8, 8, 0><<<dim3(128, 8), 256, 0, stream>>>(
        actB, wmr[3], wvr[3], bi[4], nullptr, flags, actA);
    conv_gemm<512, 512, 8, 8, 2, 4, 4, 1><<<dim3(32, 8), 256, 0, stream>>>(
        actA, wmr[4], wvr[4], bi[5], noise, flags, z);

    // batchnorm + relu (NHWC == fc1 k' order)
    bn_part<<<128, 256, 0, stream>>>(z, part);
    bn_fin<<<1, 512, 0, stream>>>(part, bn_gamma, bn_beta, flags, bnsc, bnsh);
    bn_apply<<<8192, 256, 0, stream>>>(z, bnsc, bnsh, zr);

    // classifier head (split-K x8 into fc1part, then reduce+bias+relu)
    fc1_gemm_sk<<<dim3(2, 8, 8), 256, 0, stream>>>(zr, Wp, fc1part);
    fc1_reduce<<<1024, 256, 0, stream>>>(fc1part, fc1_b, flags, fc1o);
    fc2_kernel<<<256, 640, 0, stream>>>(fc1o, fc2_w, fc2_b, flags, d_out);
}